// Round 3
// baseline (7791.251 us; speedup 1.0000x reference)
//
#include <hip/hip_runtime.h>
#include <stdint.h>

#define NS 64      // samples
#define NA 256     // assets
#define NC 8       // clusters
#define NI 10      // inits
#define MAXIT 30   // lloyd iterations
#define CH 16      // kmeans chunk width (columns staged in LDS)
#define MLDS 90    // solve: max cluster size for LDS-resident elimination

typedef unsigned int u32;

struct Key { u32 x, y; };

// Threefry-2x32, 20 rounds — exact JAX semantics.
__device__ __forceinline__ void tf2x32(u32 k0, u32 k1, u32 c0, u32 c1, u32& o0, u32& o1) {
  u32 ks0 = k0, ks1 = k1, ks2 = k0 ^ k1 ^ 0x1BD11BDAu;
  u32 x0 = c0 + ks0, x1 = c1 + ks1;
#define TFR(r) { x0 += x1; x1 = (x1 << (r)) | (x1 >> (32 - (r))); x1 ^= x0; }
  TFR(13) TFR(15) TFR(26) TFR(6)
  x0 += ks1; x1 += ks2 + 1u;
  TFR(17) TFR(29) TFR(16) TFR(24)
  x0 += ks2; x1 += ks0 + 2u;
  TFR(13) TFR(15) TFR(26) TFR(6)
  x0 += ks0; x1 += ks1 + 3u;
  TFR(17) TFR(29) TFR(16) TFR(24)
  x0 += ks1; x1 += ks2 + 4u;
  TFR(13) TFR(15) TFR(26) TFR(6)
  x0 += ks2; x1 += ks0 + 5u;
#undef TFR
  o0 = x0; o1 = x1;
}

// jax_threefry_partitionable=True semantics (verified round 2):
// split(key, n)[j]              = threefry2x32(key, 0, j) -> (o0, o1)
// random_bits(key, 32, (n,))[i] = o0 ^ o1 of threefry2x32(key, 0, i)
__device__ __forceinline__ Key key_row(Key k, u32 j) {
  Key r; tf2x32(k.x, k.y, 0u, j, r.x, r.y); return r;
}
__device__ __forceinline__ u32 rbits32(Key k, u32 i) {
  u32 o0, o1; tf2x32(k.x, k.y, 0u, i, o0, o1); return o0 ^ o1;
}

// ---------------- corr (f64) ----------------
__global__ void nco_corr_kernel(const float* __restrict__ cov, double* __restrict__ corr) {
  int b = blockIdx.x;            // b = j*256 + i
  int j = b >> 8, i = b & 255, d = threadIdx.x;
  const float* C = cov + (size_t)j * NA * NA;
  double di = sqrt((double)C[i * NA + i]);
  double dd = sqrt((double)C[d * NA + d]);
  corr[(size_t)b * NA + d] = (double)C[i * NA + d] / (di * dd);
}

// ---------------- init indices (JAX PRNG chain) ----------------
__global__ void nco_init_kernel(int* __restrict__ initIdx) {
  int blk = blockIdx.x;          // j*NI + m
  int j = blk / NI, m = blk % NI;
  int t = threadIdx.x;
  __shared__ u32 bits[NA];

  Key base; base.x = 0u; base.y = 42u;          // jax.random.key(42) -> [0, 42]
  Key skey = key_row(base, (u32)j);             // split(base, 64)[j]
  Key ikey = key_row(skey, (u32)m);             // split(skey, 10)[m]
  Key sub  = key_row(ikey, 1u);                 // _shuffle subkey = split(ikey)[1]
  bits[t] = rbits32(sub, (u32)t);               // random_bits(sub, 32, (256,))
  __syncthreads();

  u32 mine = bits[t];
  int rank = 0;
  for (int u = 0; u < NA; u++) {
    u32 b2 = bits[u];
    rank += (b2 < mine) || (b2 == mine && u < t);
  }
  if (rank < NC) initIdx[blk * NC + rank] = t;
}

// ---------------- k-means (Lloyd, f64, fused single-read chunked) ----------------
// XCD swizzle: blocks with b%8==x handle samples j in {x, x+8, ...} so each
// XCD's L2 (4 MiB) holds exactly its 8 samples' corr (8 x 512 KiB).
__global__ __launch_bounds__(256) void nco_kmeans_kernel(
    const double* __restrict__ corr, const int* __restrict__ initIdx,
    int* __restrict__ ixsAll, double* __restrict__ inertiaAll) {
  int b = blockIdx.x;                 // 0..639
  int xcd = b & 7, s = b >> 3;        // s in 0..79
  int j  = xcd + 8 * (s / NI);        // sample (bijective)
  int mi = s - (s / NI) * NI;         // init
  int blk = j * NI + mi;              // original index for initIdx/ixsAll/inertia
  int t = threadIdx.x;
  const double* X = corr + (size_t)j * NA * NA;

  __shared__ double tileT[CH][NA + 1];   // transposed chunk: tileT[d][i], pad -> conflict-free
  __shared__ double cent[NC][NA];
  __shared__ int    ixs[NA];
  __shared__ double cnts[NC];
  __shared__ double cn2[NC];

  for (int c = 0; c < NC; c++) {
    int p = initIdx[blk * NC + c];
    cent[c][t] = X[(size_t)p * NA + t];
  }
  __syncthreads();

  int myix = 0;
  double mindv = 0.0;
  for (int it = 0; it <= MAXIT; ++it) {
    const bool upd = (it > 0);
    if (upd && t < NC) {               // counts from previous assignments (i-order)
      double cnt = 0.0;
      for (int i = 0; i < NA; i++) cnt += (ixs[i] == t) ? 1.0 : 0.0;
      cnts[t] = cnt;
    }
    if (t < NC) cn2[t] = 0.0;
    double acc[NC];
#pragma unroll
    for (int c = 0; c < NC; c++) acc[c] = 0.0;
    double xx = 0.0;

    for (int q = 0; q < NA / CH; q++) {
      __syncthreads();                 // prev chunk consumers done; cnts/cn2 visible
      // coalesced global -> LDS (transposed): lanes cover 16 contiguous cols per row
#pragma unroll
      for (int k = 0; k < CH; k++) {
        int f = (k << 8) | t;
        int i = f >> 4, d = f & (CH - 1);
        tileT[d][i] = X[(size_t)i * NA + (q << 4) + d];
      }
      __syncthreads();
      if (upd) {
        // center update for this chunk from PREVIOUS assignments (exact i-order sum)
        if (t < NC * CH) {
          int c = t >> 4, d = t & (CH - 1);
          double ssum = 0.0;
          for (int i = 0; i < NA; i++) ssum += (ixs[i] == c) ? tileT[d][i] : 0.0;
          double cnt = cnts[c];
          int gd = (q << 4) + d;
          if (cnt > 0.0) cent[c][gd] = ssum / fmax(cnt, 1.0);
        }
        __syncthreads();
      }
      if (t < NC) {                    // accumulate ||c||^2 over this (fresh) chunk
        double part = 0.0;
        int gd0 = q << 4;
#pragma unroll
        for (int d = 0; d < CH; d++) { double v = cent[t][gd0 + d]; part = fma(v, v, part); }
        cn2[t] += part;
      }
      {                                // cross-term partials: acc[c] += x . cent_c
        int gd0 = q << 4;
#pragma unroll
        for (int dp = 0; dp < CH; dp += 2) {
          double x0 = tileT[dp][t], x1 = tileT[dp + 1][t];
          if (it == MAXIT) { xx = fma(x0, x0, xx); xx = fma(x1, x1, xx); }
#pragma unroll
          for (int c = 0; c < NC; c++) {
            double c0 = cent[c][gd0 + dp];
            double c1 = cent[c][gd0 + dp + 1];
            acc[c] = fma(x0, c0, acc[c]);
            acc[c] = fma(x1, c1, acc[c]);
          }
        }
      }
    }
    __syncthreads();
    // argmin_c of ||c||^2 - 2 x.c  (== argmin d2; ties -> first, same as jnp.argmin)
    double fb = cn2[0] - 2.0 * acc[0]; int bi = 0;
#pragma unroll
    for (int c = 1; c < NC; c++) {
      double f = cn2[c] - 2.0 * acc[c];
      if (f < fb) { fb = f; bi = c; }
    }
    myix = bi;
    if (it == MAXIT) mindv = xx + fb;
    ixs[t] = bi;
    __syncthreads();
  }

  ((double*)tileT)[t] = mindv;         // reuse tile as scratch (exact i-order inertia sum)
  __syncthreads();
  ixsAll[blk * NA + t] = myix;
  if (t == 0) {
    double ss = 0.0;
    for (int i = 0; i < NA; i++) ss += ((double*)tileT)[i];
    inertiaAll[blk] = ss;
  }
}

// ---------------- per-sample solves + inter-cluster + output ----------------
__global__ __launch_bounds__(256) void nco_solve_kernel(
    const float* __restrict__ cov, const float* __restrict__ rets,
    const int* __restrict__ ixsAll, const double* __restrict__ inertiaAll,
    double* __restrict__ buf_all, float* __restrict__ out) {
  int j = blockIdx.x, t = threadIdx.x;
  const float* C = cov + (size_t)j * NA * NA;
  const float* r = rets + (size_t)j * NA;
  double* gbuf = buf_all + (size_t)j * NA * NA;   // global fallback (m > MLDS)

  __shared__ double bufl[MLDS * MLDS];            // 64.8 KiB LDS elimination buffer
  __shared__ int    sbest;
  __shared__ int    li[NA];
  __shared__ int    smm;
  __shared__ double rhs[NA];
  __shared__ double wsub[NA];
  __shared__ double sdenom;
  __shared__ double wc[NC][NA];     // w_cols (k, n)
  __shared__ double tmpL[NC][NA];   // w^T @ cov
  __shared__ double interA[NC][NC];
  __shared__ double interb[NC];
  __shared__ double wi[NC];

  if (t == 0) {
    double bv = inertiaAll[j * NI]; int b = 0;
    for (int m = 1; m < NI; m++) {
      double v = inertiaAll[j * NI + m];
      if (v < bv) { bv = v; b = m; }               // first-min
    }
    sbest = b;
  }
  __syncthreads();
  const int* ixs = ixsAll + (size_t)(j * NI + sbest) * NA;

  for (int c = 0; c < NC; c++) {
    if (t == 0) {
      int m = 0;
      for (int i = 0; i < NA; i++) if (ixs[i] == c) li[m++] = i;
      smm = m;
    }
    wc[c][t] = 0.0;
    __syncthreads();
    int m = smm;
    if (m > 0) {
      double* bp = (m <= MLDS) ? bufl : gbuf;
      if (t < m) {
        int ra = li[t];
        const float* Crow = C + (size_t)ra * NA;
        for (int b2 = 0; b2 < m; b2++) bp[(size_t)t * m + b2] = (double)Crow[li[b2]];
        rhs[t] = (double)r[ra];
      }
      __syncthreads();
      // Gaussian elimination (SPD submatrix -> no pivoting needed)
      for (int k = 0; k < m - 1; k++) {
        double piv = bp[(size_t)k * m + k];
        if (t > k && t < m) {
          double f = bp[(size_t)t * m + k] / piv;
          rhs[t] -= f * rhs[k];
          for (int b2 = k + 1; b2 < m; b2++)
            bp[(size_t)t * m + b2] -= f * bp[(size_t)k * m + b2];
        }
        __syncthreads();
      }
      // back substitution
      for (int a = m - 1; a >= 0; a--) {
        if (t == a) wsub[a] = rhs[a] / bp[(size_t)a * m + a];
        __syncthreads();
        if (t < a) rhs[t] -= bp[(size_t)t * m + a] * wsub[a];
        __syncthreads();
      }
      if (t == 0) {
        double s = 0.0;
        for (int a = 0; a < m; a++) s += wsub[a];
        sdenom = s;
      }
      __syncthreads();
      if (t < m) wc[c][li[t]] = (sdenom != 0.0) ? (wsub[t] / sdenom) : 0.0;
    }
    __syncthreads();
  }

  // tmpL[c][q] = sum_p wc[c][p] * cov[p][q]
  {
    double tcol[NC];
#pragma unroll
    for (int c = 0; c < NC; c++) tcol[c] = 0.0;
    for (int p = 0; p < NA; p++) {
      double cv = (double)C[(size_t)p * NA + t];
#pragma unroll
      for (int c = 0; c < NC; c++) tcol[c] += wc[c][p] * cv;
    }
#pragma unroll
    for (int c = 0; c < NC; c++) tmpL[c][t] = tcol[c];
  }
  __syncthreads();

  if (t < NC * NC) {
    int c = t / NC, c2 = t % NC;
    double s = 0.0;
    for (int q = 0; q < NA; q++) s += tmpL[c][q] * wc[c2][q];
    interA[c][c2] = s;
  }
  if (t >= 64 && t < 64 + NC) {
    int c = t - 64;
    double s = 0.0;
    for (int p = 0; p < NA; p++) s += wc[c][p] * (double)r[p];
    interb[c] = s;
  }
  __syncthreads();

  if (t == 0) {
    double A[NC][NC], bb[NC];
    for (int a = 0; a < NC; a++) {
      bb[a] = interb[a];
      for (int q = 0; q < NC; q++) A[a][q] = interA[a][q];
    }
    for (int k = 0; k < NC; k++) {
      int p = k; double mx = fabs(A[k][k]);
      for (int i2 = k + 1; i2 < NC; i2++) {
        double v = fabs(A[i2][k]);
        if (v > mx) { mx = v; p = i2; }
      }
      if (p != k) {
        for (int q = 0; q < NC; q++) { double tv = A[k][q]; A[k][q] = A[p][q]; A[p][q] = tv; }
        double tb = bb[k]; bb[k] = bb[p]; bb[p] = tb;
      }
      for (int i2 = k + 1; i2 < NC; i2++) {
        double f = A[i2][k] / A[k][k];
        bb[i2] -= f * bb[k];
        for (int q = k + 1; q < NC; q++) A[i2][q] -= f * A[k][q];
      }
    }
    double w[NC];
    for (int a = NC - 1; a >= 0; a--) {
      double s = bb[a];
      for (int q = a + 1; q < NC; q++) s -= A[a][q] * w[q];
      w[a] = s / A[a][a];
    }
    double ssum = 0.0;
    for (int a = 0; a < NC; a++) ssum += w[a];
    for (int a = 0; a < NC; a++) wi[a] = w[a] / ssum;
  }
  __syncthreads();

  double o = 0.0;
#pragma unroll
  for (int c = 0; c < NC; c++) o += wc[c][t] * wi[c];
  out[(size_t)j * NA + t] = (float)o;
}

extern "C" void kernel_launch(void* const* d_in, const int* in_sizes, int n_in,
                              void* d_out, int out_size, void* d_ws, size_t ws_size,
                              hipStream_t stream) {
  const float* cov  = (const float*)d_in[0];
  const float* rets = (const float*)d_in[1];
  float* out = (float*)d_out;
  char* ws = (char*)d_ws;

  const size_t corr_bytes = (size_t)NS * NA * NA * sizeof(double);     // 32 MiB
  double* corr       = (double*)(ws);
  int*    initIdx    = (int*)   (ws + corr_bytes);
  double* inertiaAll = (double*)(ws + corr_bytes + 20480);
  int*    ixsAll     = (int*)   (ws + corr_bytes + 20480 + 5120);
  double* buf_all    = corr;    // alias: corr dead after kmeans

  hipLaunchKernelGGL(nco_corr_kernel,   dim3(NS * NA), dim3(NA), 0, stream, cov, corr);
  hipLaunchKernelGGL(nco_init_kernel,   dim3(NS * NI), dim3(NA), 0, stream, initIdx);
  hipLaunchKernelGGL(nco_kmeans_kernel, dim3(NS * NI), dim3(NA), 0, stream,
                     corr, initIdx, ixsAll, inertiaAll);
  hipLaunchKernelGGL(nco_solve_kernel,  dim3(NS),      dim3(NA), 0, stream,
                     cov, rets, ixsAll, inertiaAll, buf_all, out);
}

// Round 4
// 2299.119 us; speedup vs baseline: 3.3888x; 3.3888x over previous
//
#include <hip/hip_runtime.h>
#include <stdint.h>

#define NS 64      // samples
#define NA 256     // assets
#define NC 8       // clusters
#define NI 10      // inits
#define MAXIT 30   // lloyd iterations
#define MLDS 90    // solve: max cluster size for LDS-resident elimination

typedef unsigned int u32;

struct Key { u32 x, y; };

// Threefry-2x32, 20 rounds — exact JAX semantics.
__device__ __forceinline__ void tf2x32(u32 k0, u32 k1, u32 c0, u32 c1, u32& o0, u32& o1) {
  u32 ks0 = k0, ks1 = k1, ks2 = k0 ^ k1 ^ 0x1BD11BDAu;
  u32 x0 = c0 + ks0, x1 = c1 + ks1;
#define TFR(r) { x0 += x1; x1 = (x1 << (r)) | (x1 >> (32 - (r))); x1 ^= x0; }
  TFR(13) TFR(15) TFR(26) TFR(6)
  x0 += ks1; x1 += ks2 + 1u;
  TFR(17) TFR(29) TFR(16) TFR(24)
  x0 += ks2; x1 += ks0 + 2u;
  TFR(13) TFR(15) TFR(26) TFR(6)
  x0 += ks0; x1 += ks1 + 3u;
  TFR(17) TFR(29) TFR(16) TFR(24)
  x0 += ks1; x1 += ks2 + 4u;
  TFR(13) TFR(15) TFR(26) TFR(6)
  x0 += ks2; x1 += ks0 + 5u;
#undef TFR
  o0 = x0; o1 = x1;
}

// jax_threefry_partitionable=True semantics (verified round 2):
// split(key, n)[j]              = threefry2x32(key, 0, j) -> (o0, o1)
// random_bits(key, 32, (n,))[i] = o0 ^ o1 of threefry2x32(key, 0, i)
__device__ __forceinline__ Key key_row(Key k, u32 j) {
  Key r; tf2x32(k.x, k.y, 0u, j, r.x, r.y); return r;
}
__device__ __forceinline__ u32 rbits32(Key k, u32 i) {
  u32 o0, o1; tf2x32(k.x, k.y, 0u, i, o0, o1); return o0 ^ o1;
}

// ---------------- corr (f64) ----------------
__global__ void nco_corr_kernel(const float* __restrict__ cov, double* __restrict__ corr) {
  int b = blockIdx.x;            // b = j*256 + i
  int j = b >> 8, i = b & 255, d = threadIdx.x;
  const float* C = cov + (size_t)j * NA * NA;
  double di = sqrt((double)C[i * NA + i]);
  double dd = sqrt((double)C[d * NA + d]);
  corr[(size_t)b * NA + d] = (double)C[i * NA + d] / (di * dd);
}

// ---------------- init indices (JAX PRNG chain) ----------------
__global__ void nco_init_kernel(int* __restrict__ initIdx) {
  int blk = blockIdx.x;          // j*NI + m
  int j = blk / NI, m = blk % NI;
  int t = threadIdx.x;
  __shared__ u32 bits[NA];

  Key base; base.x = 0u; base.y = 42u;          // jax.random.key(42) -> [0, 42]
  Key skey = key_row(base, (u32)j);             // split(base, 64)[j]
  Key ikey = key_row(skey, (u32)m);             // split(skey, 10)[m]
  Key sub  = key_row(ikey, 1u);                 // _shuffle subkey = split(ikey)[1]
  bits[t] = rbits32(sub, (u32)t);               // random_bits(sub, 32, (256,))
  __syncthreads();

  u32 mine = bits[t];
  int rank = 0;
  for (int u = 0; u < NA; u++) {
    u32 b2 = bits[u];
    rank += (b2 < mine) || (b2 == mine && u < t);
  }
  if (rank < NC) initIdx[blk * NC + rank] = t;
}

// ---------------- k-means (Lloyd, f64, symmetric column-sweep) ----------------
// Both phases stream corr column-major (coalesced; corr is symmetric so the
// update's column access IS a row access). No X staging in LDS -> no bank
// conflicts; 3 barriers/iter. XCD swizzle keeps each XCD's 8 samples (4 MiB)
// resident in its L2.
__global__ __launch_bounds__(256) void nco_kmeans_kernel(
    const double* __restrict__ corr, const int* __restrict__ initIdx,
    int* __restrict__ ixsAll, double* __restrict__ inertiaAll) {
  int b = blockIdx.x;                 // 0..639
  int xcd = b & 7, s = b >> 3;        // s in 0..79
  int j  = xcd + 8 * (s / NI);        // sample (bijective)
  int mi = s - (s / NI) * NI;         // init
  int blk = j * NI + mi;              // original index for initIdx/ixsAll/inertia
  int t = threadIdx.x;
  int w = t >> 6;                     // wave id (4 waves)
  const double* X = corr + (size_t)j * NA * NA;

  __shared__ double cent[NC][NA];     // 16 KiB [c][d]
  __shared__ double Mw[NC][NA];       // 16 KiB binary onehot M[c][i]
  __shared__ int    ixs[NA];
  __shared__ double cnts[NC];
  __shared__ double wcnt[4][NC];

  for (int c = 0; c < NC; c++) {
    int p = initIdx[blk * NC + c];
    cent[c][t] = X[(size_t)p * NA + t];   // coalesced row read
  }
  __syncthreads();

  int myix = 0;
  double mind = 0.0;
  for (int it = 0; it <= MAXIT; ++it) {
    if (it > 0) {
      int myc = ixs[t];
#pragma unroll
      for (int c = 0; c < NC; c++) {
        Mw[c][t] = (myc == c) ? 1.0 : 0.0;
        unsigned long long bal = __ballot(myc == c);
        if ((t & 63) == 0) wcnt[w][c] = (double)__popcll(bal);
      }
      __syncthreads();                 // Mw, wcnt visible
      if (t < NC) cnts[t] = wcnt[0][t] + wcnt[1][t] + wcnt[2][t] + wcnt[3][t];

      // update pass: cent[c][t] = sum_i M[c][i] * X[i][t]  (exact i-order; fma
      // with multipliers 1.0/0.0 == predicated add, matches reference sums)
      double sacc[NC];
#pragma unroll
      for (int c = 0; c < NC; c++) sacc[c] = 0.0;
      for (int i = 0; i < NA; i += 2) {
        double x0 = X[(size_t)i * NA + t];         // coalesced
        double x1 = X[(size_t)(i + 1) * NA + t];
#pragma unroll
        for (int c = 0; c < NC; c++) {
          sacc[c] = fma(Mw[c][i], x0, sacc[c]);    // Mw broadcast (uniform addr)
          sacc[c] = fma(Mw[c][i + 1], x1, sacc[c]);
        }
      }
      __syncthreads();                 // cnts visible; prev cent reads long done
#pragma unroll
      for (int c = 0; c < NC; c++) {
        double cnt = cnts[c];
        if (cnt > 0.0) cent[c][t] = sacc[c] / fmax(cnt, 1.0);
      }
      __syncthreads();                 // new cent visible for distance pass
    }

    // distance pass: acc[c] = sum_d (x_d - cent[c][d])^2, d-ascending
    double acc[NC];
#pragma unroll
    for (int c = 0; c < NC; c++) acc[c] = 0.0;
    for (int d = 0; d < NA; d += 2) {
      double x0 = X[(size_t)d * NA + t];           // coalesced
      double x1 = X[(size_t)(d + 1) * NA + t];
#pragma unroll
      for (int c = 0; c < NC; c++) {
        double df0 = x0 - cent[c][d];              // cent broadcast
        acc[c] = fma(df0, df0, acc[c]);
        double df1 = x1 - cent[c][d + 1];
        acc[c] = fma(df1, df1, acc[c]);
      }
    }
    double best = acc[0]; int bi = 0;
#pragma unroll
    for (int c = 1; c < NC; c++)
      if (acc[c] < best) { best = acc[c]; bi = c; }  // first-min = jnp.argmin
    myix = bi;
    if (it == MAXIT) mind = best;
    ixs[t] = bi;
    __syncthreads();                   // ixs visible; separates cent read/write
  }

  double* red = &Mw[0][0];             // reuse Mw as inertia scratch
  red[t] = mind;
  __syncthreads();
  ixsAll[blk * NA + t] = myix;
  if (t == 0) {
    double ss = 0.0;
    for (int i = 0; i < NA; i++) ss += red[i];     // exact i-order
    inertiaAll[blk] = ss;
  }
}

// ---------------- per-sample solves + inter-cluster + output ----------------
__global__ __launch_bounds__(256) void nco_solve_kernel(
    const float* __restrict__ cov, const float* __restrict__ rets,
    const int* __restrict__ ixsAll, const double* __restrict__ inertiaAll,
    double* __restrict__ buf_all, float* __restrict__ out) {
  int j = blockIdx.x, t = threadIdx.x;
  const float* C = cov + (size_t)j * NA * NA;
  const float* r = rets + (size_t)j * NA;
  double* gbuf = buf_all + (size_t)j * NA * NA;   // global fallback (m > MLDS)

  __shared__ double bufl[MLDS * MLDS];            // 64.8 KiB LDS elimination buffer
  __shared__ int    sbest;
  __shared__ int    li[NA];
  __shared__ int    smm;
  __shared__ double rhs[NA];
  __shared__ double wsub[NA];
  __shared__ double sdenom;
  __shared__ double wc[NC][NA];     // w_cols (k, n)
  __shared__ double tmpL[NC][NA];   // w^T @ cov
  __shared__ double interA[NC][NC];
  __shared__ double interb[NC];
  __shared__ double wi[NC];

  if (t == 0) {
    double bv = inertiaAll[j * NI]; int b = 0;
    for (int m = 1; m < NI; m++) {
      double v = inertiaAll[j * NI + m];
      if (v < bv) { bv = v; b = m; }               // first-min
    }
    sbest = b;
  }
  __syncthreads();
  const int* ixs = ixsAll + (size_t)(j * NI + sbest) * NA;

  for (int c = 0; c < NC; c++) {
    if (t == 0) {
      int m = 0;
      for (int i = 0; i < NA; i++) if (ixs[i] == c) li[m++] = i;
      smm = m;
    }
    wc[c][t] = 0.0;
    __syncthreads();
    int m = smm;
    if (m > 0) {
      double* bp = (m <= MLDS) ? bufl : gbuf;
      if (t < m) {
        int ra = li[t];
        const float* Crow = C + (size_t)ra * NA;
        for (int b2 = 0; b2 < m; b2++) bp[(size_t)t * m + b2] = (double)Crow[li[b2]];
        rhs[t] = (double)r[ra];
      }
      __syncthreads();
      // Gaussian elimination (SPD submatrix -> no pivoting needed)
      for (int k = 0; k < m - 1; k++) {
        double piv = bp[(size_t)k * m + k];
        if (t > k && t < m) {
          double f = bp[(size_t)t * m + k] / piv;
          rhs[t] -= f * rhs[k];
          for (int b2 = k + 1; b2 < m; b2++)
            bp[(size_t)t * m + b2] -= f * bp[(size_t)k * m + b2];
        }
        __syncthreads();
      }
      // back substitution
      for (int a = m - 1; a >= 0; a--) {
        if (t == a) wsub[a] = rhs[a] / bp[(size_t)a * m + a];
        __syncthreads();
        if (t < a) rhs[t] -= bp[(size_t)t * m + a] * wsub[a];
        __syncthreads();
      }
      if (t == 0) {
        double s = 0.0;
        for (int a = 0; a < m; a++) s += wsub[a];
        sdenom = s;
      }
      __syncthreads();
      if (t < m) wc[c][li[t]] = (sdenom != 0.0) ? (wsub[t] / sdenom) : 0.0;
    }
    __syncthreads();
  }

  // tmpL[c][q] = sum_p wc[c][p] * cov[p][q]
  {
    double tcol[NC];
#pragma unroll
    for (int c = 0; c < NC; c++) tcol[c] = 0.0;
    for (int p = 0; p < NA; p++) {
      double cv = (double)C[(size_t)p * NA + t];
#pragma unroll
      for (int c = 0; c < NC; c++) tcol[c] += wc[c][p] * cv;
    }
#pragma unroll
    for (int c = 0; c < NC; c++) tmpL[c][t] = tcol[c];
  }
  __syncthreads();

  if (t < NC * NC) {
    int c = t / NC, c2 = t % NC;
    double s = 0.0;
    for (int q = 0; q < NA; q++) s += tmpL[c][q] * wc[c2][q];
    interA[c][c2] = s;
  }
  if (t >= 64 && t < 64 + NC) {
    int c = t - 64;
    double s = 0.0;
    for (int p = 0; p < NA; p++) s += wc[c][p] * (double)r[p];
    interb[c] = s;
  }
  __syncthreads();

  if (t == 0) {
    double A[NC][NC], bb[NC];
    for (int a = 0; a < NC; a++) {
      bb[a] = interb[a];
      for (int q = 0; q < NC; q++) A[a][q] = interA[a][q];
    }
    for (int k = 0; k < NC; k++) {
      int p = k; double mx = fabs(A[k][k]);
      for (int i2 = k + 1; i2 < NC; i2++) {
        double v = fabs(A[i2][k]);
        if (v > mx) { mx = v; p = i2; }
      }
      if (p != k) {
        for (int q = 0; q < NC; q++) { double tv = A[k][q]; A[k][q] = A[p][q]; A[p][q] = tv; }
        double tb = bb[k]; bb[k] = bb[p]; bb[p] = tb;
      }
      for (int i2 = k + 1; i2 < NC; i2++) {
        double f = A[i2][k] / A[k][k];
        bb[i2] -= f * bb[k];
        for (int q = k + 1; q < NC; q++) A[i2][q] -= f * A[k][q];
      }
    }
    double w[NC];
    for (int a = NC - 1; a >= 0; a--) {
      double s = bb[a];
      for (int q = a + 1; q < NC; q++) s -= A[a][q] * w[q];
      w[a] = s / A[a][a];
    }
    double ssum = 0.0;
    for (int a = 0; a < NC; a++) ssum += w[a];
    for (int a = 0; a < NC; a++) wi[a] = w[a] / ssum;
  }
  __syncthreads();

  double o = 0.0;
#pragma unroll
  for (int c = 0; c < NC; c++) o += wc[c][t] * wi[c];
  out[(size_t)j * NA + t] = (float)o;
}

extern "C" void kernel_launch(void* const* d_in, const int* in_sizes, int n_in,
                              void* d_out, int out_size, void* d_ws, size_t ws_size,
                              hipStream_t stream) {
  const float* cov  = (const float*)d_in[0];
  const float* rets = (const float*)d_in[1];
  float* out = (float*)d_out;
  char* ws = (char*)d_ws;

  const size_t corr_bytes = (size_t)NS * NA * NA * sizeof(double);     // 32 MiB
  double* corr       = (double*)(ws);
  int*    initIdx    = (int*)   (ws + corr_bytes);
  double* inertiaAll = (double*)(ws + corr_bytes + 20480);
  int*    ixsAll     = (int*)   (ws + corr_bytes + 20480 + 5120);
  double* buf_all    = corr;    // alias: corr dead after kmeans

  hipLaunchKernelGGL(nco_corr_kernel,   dim3(NS * NA), dim3(NA), 0, stream, cov, corr);
  hipLaunchKernelGGL(nco_init_kernel,   dim3(NS * NI), dim3(NA), 0, stream, initIdx);
  hipLaunchKernelGGL(nco_kmeans_kernel, dim3(NS * NI), dim3(NA), 0, stream,
                     corr, initIdx, ixsAll, inertiaAll);
  hipLaunchKernelGGL(nco_solve_kernel,  dim3(NS),      dim3(NA), 0, stream,
                     cov, rets, ixsAll, inertiaAll, buf_all, out);
}

// Round 5
// 728.830 us; speedup vs baseline: 10.6901x; 3.1545x over previous
//
#include <hip/hip_runtime.h>
#include <stdint.h>

#define NS 64      // samples
#define NA 256     // assets
#define NC 8       // clusters
#define NI 10      // inits
#define MAXIT 30   // lloyd iterations
#define MLDS 90    // solve: max cluster size for LDS-resident elimination

typedef unsigned int u32;

struct Key { u32 x, y; };

// Threefry-2x32, 20 rounds — exact JAX semantics.
__device__ __forceinline__ void tf2x32(u32 k0, u32 k1, u32 c0, u32 c1, u32& o0, u32& o1) {
  u32 ks0 = k0, ks1 = k1, ks2 = k0 ^ k1 ^ 0x1BD11BDAu;
  u32 x0 = c0 + ks0, x1 = c1 + ks1;
#define TFR(r) { x0 += x1; x1 = (x1 << (r)) | (x1 >> (32 - (r))); x1 ^= x0; }
  TFR(13) TFR(15) TFR(26) TFR(6)
  x0 += ks1; x1 += ks2 + 1u;
  TFR(17) TFR(29) TFR(16) TFR(24)
  x0 += ks2; x1 += ks0 + 2u;
  TFR(13) TFR(15) TFR(26) TFR(6)
  x0 += ks0; x1 += ks1 + 3u;
  TFR(17) TFR(29) TFR(16) TFR(24)
  x0 += ks1; x1 += ks2 + 4u;
  TFR(13) TFR(15) TFR(26) TFR(6)
  x0 += ks2; x1 += ks0 + 5u;
#undef TFR
  o0 = x0; o1 = x1;
}

// jax_threefry_partitionable=True semantics (verified round 2):
// split(key, n)[j]              = threefry2x32(key, 0, j) -> (o0, o1)
// random_bits(key, 32, (n,))[i] = o0 ^ o1 of threefry2x32(key, 0, i)
__device__ __forceinline__ Key key_row(Key k, u32 j) {
  Key r; tf2x32(k.x, k.y, 0u, j, r.x, r.y); return r;
}
__device__ __forceinline__ u32 rbits32(Key k, u32 i) {
  u32 o0, o1; tf2x32(k.x, k.y, 0u, i, o0, o1); return o0 ^ o1;
}

// ---------------- corr (f64) ----------------
__global__ void nco_corr_kernel(const float* __restrict__ cov, double* __restrict__ corr) {
  int b = blockIdx.x;            // b = j*256 + i
  int j = b >> 8, i = b & 255, d = threadIdx.x;
  const float* C = cov + (size_t)j * NA * NA;
  double di = sqrt((double)C[i * NA + i]);
  double dd = sqrt((double)C[d * NA + d]);
  corr[(size_t)b * NA + d] = (double)C[i * NA + d] / (di * dd);
}

// ---------------- init indices (JAX PRNG chain) ----------------
__global__ void nco_init_kernel(int* __restrict__ initIdx) {
  int blk = blockIdx.x;          // j*NI + m
  int j = blk / NI, m = blk % NI;
  int t = threadIdx.x;
  __shared__ u32 bits[NA];

  Key base; base.x = 0u; base.y = 42u;          // jax.random.key(42) -> [0, 42]
  Key skey = key_row(base, (u32)j);             // split(base, 64)[j]
  Key ikey = key_row(skey, (u32)m);             // split(skey, 10)[m]
  Key sub  = key_row(ikey, 1u);                 // _shuffle subkey = split(ikey)[1]
  bits[t] = rbits32(sub, (u32)t);               // random_bits(sub, 32, (256,))
  __syncthreads();

  u32 mine = bits[t];
  int rank = 0;
  for (int u = 0; u < NA; u++) {
    u32 b2 = bits[u];
    rank += (b2 < mine) || (b2 == mine && u < t);
  }
  if (rank < NC) initIdx[blk * NC + rank] = t;
}

// ---------------- k-means (Lloyd, f64, column-sweep + early exit) ----------------
// Early exit: if assignments are unchanged vs previous iteration, the state is
// a fixed point (centers/distances/inertia frozen) -> breaking is bit-exact.
// Cross-term distance argmin (verified round 3). XCD swizzle keeps each XCD's
// 8 samples (4 MiB) resident in its L2.
__global__ __launch_bounds__(256) void nco_kmeans_kernel(
    const double* __restrict__ corr, const int* __restrict__ initIdx,
    int* __restrict__ ixsAll, double* __restrict__ inertiaAll) {
  int b = blockIdx.x;                 // 0..639
  int xcd = b & 7, s = b >> 3;        // s in 0..79
  int j  = xcd + 8 * (s / NI);        // sample (bijective)
  int mi = s - (s / NI) * NI;         // init
  int blk = j * NI + mi;              // original index
  int t = threadIdx.x;
  int w = t >> 6;                     // wave id
  const double* X = corr + (size_t)j * NA * NA;

  __shared__ double cent[NC][NA];     // 16 KiB [c][d]
  __shared__ double Mw[NC][NA];       // 16 KiB binary onehot M[c][i]
  __shared__ double pcn[NC][32];
  __shared__ double cnts[NC];
  __shared__ double cn2[NC];
  __shared__ double wcnt[4][NC];
  __shared__ int    wch[4];

  for (int c = 0; c < NC; c++) {
    int p = initIdx[blk * NC + c];
    cent[c][t] = X[(size_t)p * NA + t];   // coalesced row read
  }
  __syncthreads();

  int myix = -1;                       // forces "changed" on iter 0
  double xx = 0.0, fb = 0.0;
  for (int it = 0; it <= MAXIT; ++it) {
    if (it > 0) {
      int myc = myix;
#pragma unroll
      for (int c = 0; c < NC; c++) {
        Mw[c][t] = (myc == c) ? 1.0 : 0.0;
        unsigned long long bal = __ballot(myc == c);
        if ((t & 63) == 0) wcnt[w][c] = (double)__popcll(bal);
      }
      __syncthreads();                 // (A) Mw + wcnt visible
      if (t < NC) cnts[t] = wcnt[0][t] + wcnt[1][t] + wcnt[2][t] + wcnt[3][t];

      // update: cent[c][t] = sum_i M[c][i] * X[i][t]  (exact i-order, fma with
      // 1.0/0.0 == predicated add — bit-identical to the round-4 passing sums)
      double sacc[NC];
#pragma unroll
      for (int c = 0; c < NC; c++) sacc[c] = 0.0;
      for (int i = 0; i < NA; i += 4) {
        double x0 = X[(size_t)i * NA + t];
        double x1 = X[(size_t)(i + 1) * NA + t];
        double x2 = X[(size_t)(i + 2) * NA + t];
        double x3 = X[(size_t)(i + 3) * NA + t];
#pragma unroll
        for (int c = 0; c < NC; c++) {
          sacc[c] = fma(Mw[c][i], x0, sacc[c]);
          sacc[c] = fma(Mw[c][i + 1], x1, sacc[c]);
          sacc[c] = fma(Mw[c][i + 2], x2, sacc[c]);
          sacc[c] = fma(Mw[c][i + 3], x3, sacc[c]);
        }
      }
      __syncthreads();                 // (B) cnts visible, sweep done
#pragma unroll
      for (int c = 0; c < NC; c++) {
        double cnt = cnts[c];
        if (cnt > 0.0) cent[c][t] = sacc[c] / fmax(cnt, 1.0);
      }
      __syncthreads();                 // (C) new cent visible
    }

    // ||c||^2 (parallel partials; our-numeric order, argmin margin >> 1e-13)
    {
      int c = t >> 5, k = t & 31;
      const double* cr = &cent[c][k << 3];
      double p = 0.0;
#pragma unroll
      for (int d = 0; d < 8; d++) p = fma(cr[d], cr[d], p);
      pcn[c][k] = p;
    }
    __syncthreads();                   // (D)
    if (t < NC) {
      double ssum = 0.0;
      for (int k = 0; k < 32; k++) ssum += pcn[t][k];
      cn2[t] = ssum;
    }
    __syncthreads();                   // (D2)

    // distance pass: acc[c] = x . cent_c; score = ||c||^2 - 2 acc
    double acc[NC];
#pragma unroll
    for (int c = 0; c < NC; c++) acc[c] = 0.0;
    for (int d = 0; d < NA; d += 4) {
      double x0 = X[(size_t)d * NA + t];
      double x1 = X[(size_t)(d + 1) * NA + t];
      double x2 = X[(size_t)(d + 2) * NA + t];
      double x3 = X[(size_t)(d + 3) * NA + t];
      if (it == 0) {                   // ||x||^2 once (iteration-invariant)
        xx = fma(x0, x0, xx); xx = fma(x1, x1, xx);
        xx = fma(x2, x2, xx); xx = fma(x3, x3, xx);
      }
#pragma unroll
      for (int c = 0; c < NC; c++) {
        acc[c] = fma(x0, cent[c][d], acc[c]);
        acc[c] = fma(x1, cent[c][d + 1], acc[c]);
        acc[c] = fma(x2, cent[c][d + 2], acc[c]);
        acc[c] = fma(x3, cent[c][d + 3], acc[c]);
      }
    }
    double best = cn2[0] - 2.0 * acc[0]; int bi = 0;
#pragma unroll
    for (int c = 1; c < NC; c++) {
      double f = cn2[c] - 2.0 * acc[c];
      if (f < best) { best = f; bi = c; }   // first-min = jnp.argmin
    }
    fb = best;
    bool ch = (bi != myix);
    unsigned long long bal = __ballot(ch);
    if ((t & 63) == 0) wch[w] = (bal != 0ULL) ? 1 : 0;
    myix = bi;
    __syncthreads();                   // (E) wch visible; cent safe to rewrite
    if (!(wch[0] | wch[1] | wch[2] | wch[3])) break;   // fixed point: bit-exact
  }
  double mind = xx + fb;

  double* red = &Mw[0][0];             // reuse Mw as inertia scratch
  red[t] = mind;
  __syncthreads();
  ixsAll[blk * NA + t] = myix;
  if (t == 0) {
    double ss = 0.0;
    for (int i = 0; i < NA; i++) ss += red[i];     // exact i-order
    inertiaAll[blk] = ss;
  }
}

// ---------------- per-(sample,cluster) masked Markowitz solve ----------------
__global__ __launch_bounds__(256) void nco_csolve_kernel(
    const float* __restrict__ cov, const float* __restrict__ rets,
    const int* __restrict__ ixsAll, const double* __restrict__ inertiaAll,
    double* __restrict__ gbuf_all, double* __restrict__ wc_all) {
  int b = blockIdx.x;                 // j*NC + c
  int j = b >> 3, c = b & 7;
  int t = threadIdx.x;
  const float* C = cov + (size_t)j * NA * NA;
  const float* r = rets + (size_t)j * NA;

  __shared__ double bufl[MLDS * MLDS];            // 64.8 KiB
  __shared__ int    li[NA];
  __shared__ int    sm, soff, sbest;
  __shared__ double rhs[NA];
  __shared__ double wsub[NA];
  __shared__ double sdenom;

  if (t == 0) {
    double bv = inertiaAll[j * NI]; int bb = 0;
    for (int m = 1; m < NI; m++) {
      double v = inertiaAll[j * NI + m];
      if (v < bv) { bv = v; bb = m; }             // first-min
    }
    sbest = bb;
  }
  __syncthreads();
  const int* ixs = ixsAll + (size_t)(j * NI + sbest) * NA;

  double* wcc = wc_all + ((size_t)j * NC + c) * NA;
  wcc[t] = 0.0;                        // zero this cluster's weight column

  if (t == 0) {
    int cnt[NC] = {0, 0, 0, 0, 0, 0, 0, 0};
    for (int i = 0; i < NA; i++) cnt[ixs[i]]++;
    int off = 0;
    for (int u = 0; u < c; u++) off += cnt[u] * cnt[u];   // packed: sum m^2 <= 256^2
    soff = off;
    int m2 = 0;
    for (int i = 0; i < NA; i++) if (ixs[i] == c) li[m2++] = i;
    sm = m2;
  }
  __syncthreads();
  int m = sm;
  if (m == 0) return;                  // uniform exit; column stays zero

  double* bp = (m <= MLDS) ? bufl : (gbuf_all + (size_t)j * NA * NA + soff);
  if (t < m) {
    int ra = li[t];
    const float* Crow = C + (size_t)ra * NA;
    for (int b2 = 0; b2 < m; b2++) bp[(size_t)t * m + b2] = (double)Crow[li[b2]];
    rhs[t] = (double)r[ra];
  }
  __syncthreads();
  // Gaussian elimination (SPD submatrix -> no pivoting)
  for (int k = 0; k < m - 1; k++) {
    double piv = bp[(size_t)k * m + k];
    if (t > k && t < m) {
      double f = bp[(size_t)t * m + k] / piv;
      rhs[t] -= f * rhs[k];
      for (int b2 = k + 1; b2 < m; b2++)
        bp[(size_t)t * m + b2] -= f * bp[(size_t)k * m + b2];
    }
    __syncthreads();
  }
  // back substitution
  for (int a = m - 1; a >= 0; a--) {
    if (t == a) wsub[a] = rhs[a] / bp[(size_t)a * m + a];
    __syncthreads();
    if (t < a) rhs[t] -= bp[(size_t)t * m + a] * wsub[a];
    __syncthreads();
  }
  if (t == 0) {
    double ssum = 0.0;
    for (int a = 0; a < m; a++) ssum += wsub[a];
    sdenom = ssum;
  }
  __syncthreads();
  if (t < m) wcc[li[t]] = (sdenom != 0.0) ? (wsub[t] / sdenom) : 0.0;
}

// ---------------- per-sample inter-cluster assembly + output ----------------
__global__ __launch_bounds__(256) void nco_inter_kernel(
    const float* __restrict__ cov, const float* __restrict__ rets,
    const double* __restrict__ wc_all, float* __restrict__ out) {
  int j = blockIdx.x, t = threadIdx.x;
  const float* C = cov + (size_t)j * NA * NA;
  const float* r = rets + (size_t)j * NA;

  __shared__ double wc[NC][NA];
  __shared__ double tmpL[NC][NA];
  __shared__ double interA[NC][NC];
  __shared__ double interb[NC];
  __shared__ double wi[NC];

  for (int c = 0; c < NC; c++) wc[c][t] = wc_all[((size_t)j * NC + c) * NA + t];
  __syncthreads();

  // tmpL[c][q] = sum_p wc[c][p] * cov[p][q]
  {
    double tcol[NC];
#pragma unroll
    for (int c = 0; c < NC; c++) tcol[c] = 0.0;
    for (int p = 0; p < NA; p++) {
      double cv = (double)C[(size_t)p * NA + t];
#pragma unroll
      for (int c = 0; c < NC; c++) tcol[c] += wc[c][p] * cv;
    }
#pragma unroll
    for (int c = 0; c < NC; c++) tmpL[c][t] = tcol[c];
  }
  __syncthreads();

  if (t < NC * NC) {
    int c = t / NC, c2 = t % NC;
    double s = 0.0;
    for (int q = 0; q < NA; q++) s += tmpL[c][q] * wc[c2][q];
    interA[c][c2] = s;
  }
  if (t >= 64 && t < 64 + NC) {
    int c = t - 64;
    double s = 0.0;
    for (int p = 0; p < NA; p++) s += wc[c][p] * (double)r[p];
    interb[c] = s;
  }
  __syncthreads();

  if (t == 0) {
    double A[NC][NC], bb[NC];
    for (int a = 0; a < NC; a++) {
      bb[a] = interb[a];
      for (int q = 0; q < NC; q++) A[a][q] = interA[a][q];
    }
    for (int k = 0; k < NC; k++) {
      int p = k; double mx = fabs(A[k][k]);
      for (int i2 = k + 1; i2 < NC; i2++) {
        double v = fabs(A[i2][k]);
        if (v > mx) { mx = v; p = i2; }
      }
      if (p != k) {
        for (int q = 0; q < NC; q++) { double tv = A[k][q]; A[k][q] = A[p][q]; A[p][q] = tv; }
        double tb = bb[k]; bb[k] = bb[p]; bb[p] = tb;
      }
      for (int i2 = k + 1; i2 < NC; i2++) {
        double f = A[i2][k] / A[k][k];
        bb[i2] -= f * bb[k];
        for (int q = k + 1; q < NC; q++) A[i2][q] -= f * A[k][q];
      }
    }
    double w[NC];
    for (int a = NC - 1; a >= 0; a--) {
      double s = bb[a];
      for (int q = a + 1; q < NC; q++) s -= A[a][q] * w[q];
      w[a] = s / A[a][a];
    }
    double ssum = 0.0;
    for (int a = 0; a < NC; a++) ssum += w[a];
    for (int a = 0; a < NC; a++) wi[a] = w[a] / ssum;
  }
  __syncthreads();

  double o = 0.0;
#pragma unroll
  for (int c = 0; c < NC; c++) o += wc[c][t] * wi[c];
  out[(size_t)j * NA + t] = (float)o;
}

extern "C" void kernel_launch(void* const* d_in, const int* in_sizes, int n_in,
                              void* d_out, int out_size, void* d_ws, size_t ws_size,
                              hipStream_t stream) {
  const float* cov  = (const float*)d_in[0];
  const float* rets = (const float*)d_in[1];
  float* out = (float*)d_out;
  char* ws = (char*)d_ws;

  const size_t corr_bytes = (size_t)NS * NA * NA * sizeof(double);     // 32 MiB
  double* corr       = (double*)(ws);
  int*    initIdx    = (int*)   (ws + corr_bytes);                     // 20480 B
  double* inertiaAll = (double*)(ws + corr_bytes + 20480);             // 5120 B
  int*    ixsAll     = (int*)   (ws + corr_bytes + 20480 + 5120);      // 655360 B
  double* wc_all     = (double*)(ws + corr_bytes + 20480 + 5120 + 655360); // 1 MiB
  double* gbuf_all   = corr;    // alias: corr dead after kmeans

  hipLaunchKernelGGL(nco_corr_kernel,   dim3(NS * NA), dim3(NA), 0, stream, cov, corr);
  hipLaunchKernelGGL(nco_init_kernel,   dim3(NS * NI), dim3(NA), 0, stream, initIdx);
  hipLaunchKernelGGL(nco_kmeans_kernel, dim3(NS * NI), dim3(NA), 0, stream,
                     corr, initIdx, ixsAll, inertiaAll);
  hipLaunchKernelGGL(nco_csolve_kernel, dim3(NS * NC), dim3(NA), 0, stream,
                     cov, rets, ixsAll, inertiaAll, gbuf_all, wc_all);
  hipLaunchKernelGGL(nco_inter_kernel,  dim3(NS),      dim3(NA), 0, stream,
                     cov, rets, wc_all, out);
}

// Round 6
// 506.666 us; speedup vs baseline: 15.3775x; 1.4385x over previous
//
#include <hip/hip_runtime.h>
#include <stdint.h>

#define NS 64      // samples
#define NA 256     // assets
#define NC 8       // clusters
#define NI 10      // inits
#define MAXIT 30   // lloyd iterations
#define MLDS 90    // solve: max cluster size for LDS-resident elimination
#define GT 64      // gram tile

typedef unsigned int u32;

struct Key { u32 x, y; };

// Threefry-2x32, 20 rounds — exact JAX semantics.
__device__ __forceinline__ void tf2x32(u32 k0, u32 k1, u32 c0, u32 c1, u32& o0, u32& o1) {
  u32 ks0 = k0, ks1 = k1, ks2 = k0 ^ k1 ^ 0x1BD11BDAu;
  u32 x0 = c0 + ks0, x1 = c1 + ks1;
#define TFR(r) { x0 += x1; x1 = (x1 << (r)) | (x1 >> (32 - (r))); x1 ^= x0; }
  TFR(13) TFR(15) TFR(26) TFR(6)
  x0 += ks1; x1 += ks2 + 1u;
  TFR(17) TFR(29) TFR(16) TFR(24)
  x0 += ks2; x1 += ks0 + 2u;
  TFR(13) TFR(15) TFR(26) TFR(6)
  x0 += ks0; x1 += ks1 + 3u;
  TFR(17) TFR(29) TFR(16) TFR(24)
  x0 += ks1; x1 += ks2 + 4u;
  TFR(13) TFR(15) TFR(26) TFR(6)
  x0 += ks2; x1 += ks0 + 5u;
#undef TFR
  o0 = x0; o1 = x1;
}

// jax_threefry_partitionable=True semantics (verified round 2):
// split(key, n)[j]              = threefry2x32(key, 0, j) -> (o0, o1)
// random_bits(key, 32, (n,))[i] = o0 ^ o1 of threefry2x32(key, 0, i)
__device__ __forceinline__ Key key_row(Key k, u32 j) {
  Key r; tf2x32(k.x, k.y, 0u, j, r.x, r.y); return r;
}
__device__ __forceinline__ u32 rbits32(Key k, u32 i) {
  u32 o0, o1; tf2x32(k.x, k.y, 0u, i, o0, o1); return o0 ^ o1;
}

// ---------------- inv sqrt of diagonal (f64) ----------------
__global__ void nco_invs_kernel(const float* __restrict__ cov, double* __restrict__ invs) {
  int j = blockIdx.x, t = threadIdx.x;
  invs[(size_t)j * NA + t] = 1.0 / sqrt((double)cov[(size_t)j * NA * NA + (size_t)t * NA + t]);
}

// ---------------- Gram matrix G = corr * corr^T (f64), corr never materialized --------
__global__ __launch_bounds__(256) void nco_gram_kernel(
    const float* __restrict__ cov, const double* __restrict__ invs,
    double* __restrict__ G) {
  int b = blockIdx.x;                 // j*16 + tile
  int j = b >> 4, tile = b & 15;
  int ti2 = tile >> 2, tj2 = tile & 3;
  const float* C = cov + (size_t)j * NA * NA;
  const double* inv = invs + (size_t)j * NA;
  double* Gj = G + (size_t)j * NA * NA;

  __shared__ double As[16][GT + 1];   // As[kk][row]
  __shared__ double Bs[16][GT + 1];
  int t = threadIdx.x;
  int tr = t >> 4, tc = t & 15;       // 16x16 thread tile, each 4x4 out

  double acc[4][4];
#pragma unroll
  for (int a = 0; a < 4; a++)
#pragma unroll
    for (int bb = 0; bb < 4; bb++) acc[a][bb] = 0.0;

  for (int k0 = 0; k0 < NA; k0 += 16) {
    int kk = t & 15, rr = t >> 4;
    double ck = inv[k0 + kk];
#pragma unroll
    for (int m = 0; m < 4; m++) {
      int r = rr + 16 * m;
      int gr = ti2 * 64 + r;
      As[kk][r] = (double)C[(size_t)gr * NA + k0 + kk] * inv[gr] * ck;
      int gc = tj2 * 64 + r;
      Bs[kk][r] = (double)C[(size_t)gc * NA + k0 + kk] * inv[gc] * ck;
    }
    __syncthreads();
#pragma unroll
    for (int kk2 = 0; kk2 < 16; kk2++) {
      double ar[4], br[4];
#pragma unroll
      for (int m = 0; m < 4; m++) ar[m] = As[kk2][tr + 16 * m];
#pragma unroll
      for (int m = 0; m < 4; m++) br[m] = Bs[kk2][tc + 16 * m];
#pragma unroll
      for (int a = 0; a < 4; a++)
#pragma unroll
        for (int bb = 0; bb < 4; bb++) acc[a][bb] = fma(ar[a], br[bb], acc[a][bb]);
    }
    __syncthreads();
  }
#pragma unroll
  for (int a = 0; a < 4; a++) {
    int gr = ti2 * 64 + tr + 16 * a;
#pragma unroll
    for (int bb = 0; bb < 4; bb++) {
      int gc = tj2 * 64 + tc + 16 * bb;
      Gj[(size_t)gr * NA + gc] = acc[a][bb];
    }
  }
}

// ---------------- init indices (JAX PRNG chain) ----------------
__global__ void nco_init_kernel(int* __restrict__ initIdx) {
  int blk = blockIdx.x;          // j*NI + m
  int j = blk / NI, m = blk % NI;
  int t = threadIdx.x;
  __shared__ u32 bits[NA];

  Key base; base.x = 0u; base.y = 42u;          // jax.random.key(42) -> [0, 42]
  Key skey = key_row(base, (u32)j);             // split(base, 64)[j]
  Key ikey = key_row(skey, (u32)m);             // split(skey, 10)[m]
  Key sub  = key_row(ikey, 1u);                 // _shuffle subkey = split(ikey)[1]
  bits[t] = rbits32(sub, (u32)t);               // random_bits(sub, 32, (256,))
  __syncthreads();

  u32 mine = bits[t];
  int rank = 0;
  for (int u = 0; u < NA; u++) {
    u32 b2 = bits[u];
    rank += (b2 < mine) || (b2 == mine && u < t);
  }
  if (rank < NC) initIdx[blk * NC + rank] = t;
}

// ---------------- k-means (Lloyd via Gram sums + member lists + early exit) -----------
// score_k(t) = ||c_k||^2 - 2 x_t.c_k = S_k/n_k^2 - 2 s_k[t]/n_k,
// s_k[t] = sum_{i in list_k} G[i][t]  (coalesced column reads; G symmetric).
// Lists updated only when cluster non-empty -> reference frozen-center semantics.
// Init lists = singleton init points (exactly reproduces centers0). Early exit at
// assignment fixed point is bit-exact. XCD swizzle keeps 8 samples (4 MiB) per L2.
__global__ __launch_bounds__(256) void nco_kmeans_kernel(
    const double* __restrict__ G, const int* __restrict__ initIdx,
    int* __restrict__ ixsAll, double* __restrict__ inertiaAll) {
  int b = blockIdx.x;                 // 0..639
  int xcd = b & 7, s = b >> 3;
  int j  = xcd + 8 * (s / NI);        // sample (bijective)
  int mi = s - (s / NI) * NI;         // init
  int blk = j * NI + mi;
  int t = threadIdx.x;
  int w = t >> 6;
  const double* Gj = G + (size_t)j * NA * NA;

  __shared__ int    li[NC][NA];       // 8 KiB member lists
  __shared__ double sAll[NC][NA];     // 16 KiB s_k[t]
  __shared__ int    wcnt[4][NC];
  __shared__ int    nsz[NC];
  __shared__ double part[NC][8];
  __shared__ double sinvn[NC], ck2[NC];
  __shared__ int    wch[4];

  double xx = Gj[(size_t)t * NA + t];   // ||x_t||^2 (for inertia only)

  if (t < NC) { nsz[t] = 1; li[t][0] = initIdx[blk * NC + t]; }
  __syncthreads();

  int myix = -1;
  double fb = 0.0;
  for (int it = 0; it <= MAXIT; ++it) {
    if (it > 0) {
      // rebuild member lists from current assignments (non-empty clusters only)
      unsigned long long bal[NC];
#pragma unroll
      for (int k = 0; k < NC; k++) {
        bal[k] = __ballot(myix == k);
        if ((t & 63) == 0) wcnt[w][k] = (int)__popcll(bal[k]);
      }
      __syncthreads();
      if (t < NC) {
        int tot = wcnt[0][t] + wcnt[1][t] + wcnt[2][t] + wcnt[3][t];
        if (tot > 0) nsz[t] = tot;       // empty -> frozen: keep old list/size
      }
      {
        int k = myix;                    // my cluster is non-empty (contains me)
        int base = 0;
        for (int w2 = 0; w2 < w; w2++) base += wcnt[w2][k];
        unsigned long long below = bal[k] & ((1ULL << (t & 63)) - 1ULL);
        li[k][base + (int)__popcll(below)] = t;
      }
      __syncthreads();
    }

    // sweep: s_k[t] = sum over list_k of G[row][t] (coalesced, list-broadcast)
    double acc[NC];
#pragma unroll
    for (int k = 0; k < NC; k++) {
      int n = nsz[k];
      const int* lk = li[k];
      double a0 = 0.0, a1 = 0.0;
      int i = 0;
      for (; i + 4 <= n; i += 4) {
        int r0 = lk[i], r1 = lk[i + 1], r2 = lk[i + 2], r3 = lk[i + 3];
        double g0 = Gj[(size_t)r0 * NA + t];
        double g1 = Gj[(size_t)r1 * NA + t];
        double g2 = Gj[(size_t)r2 * NA + t];
        double g3 = Gj[(size_t)r3 * NA + t];
        a0 += g0; a1 += g1; a0 += g2; a1 += g3;
      }
      for (; i < n; ++i) a0 += Gj[(size_t)lk[i] * NA + t];
      acc[k] = a0 + a1;
    }
#pragma unroll
    for (int k = 0; k < NC; k++) sAll[k][t] = acc[k];
    __syncthreads();

    // S_k = sum_{t in list_k} s_k[t]  (parallel 8-way per cluster)
    if (t < 64) {
      int k = t >> 3, r = t & 7;
      int n = nsz[k];
      double p = 0.0;
      for (int i = r; i < n; i += 8) p += sAll[k][li[k][i]];
      part[k][r] = p;
    }
    __syncthreads();
    if (t < NC) {
      double S = 0.0;
#pragma unroll
      for (int r = 0; r < 8; r++) S += part[t][r];
      double inn = 1.0 / (double)nsz[t];
      sinvn[t] = inn;
      ck2[t] = S * inn * inn;
    }
    __syncthreads();

    // argmin_c score (first-min = jnp.argmin tie rule)
    double best = ck2[0] - 2.0 * acc[0] * sinvn[0]; int bi = 0;
#pragma unroll
    for (int k = 1; k < NC; k++) {
      double f = ck2[k] - 2.0 * acc[k] * sinvn[k];
      if (f < best) { best = f; bi = k; }
    }
    fb = best;
    bool ch = (bi != myix);
    unsigned long long balc = __ballot(ch);
    if ((t & 63) == 0) wch[w] = (balc != 0ULL) ? 1 : 0;
    myix = bi;
    __syncthreads();
    if (!(wch[0] | wch[1] | wch[2] | wch[3])) break;   // fixed point: bit-exact
  }

  double* red = &sAll[0][0];
  red[t] = xx + fb;                   // min d^2 of point t
  __syncthreads();
  ixsAll[blk * NA + t] = myix;
  if (t == 0) {
    double ss = 0.0;
    for (int i = 0; i < NA; i++) ss += red[i];
    inertiaAll[blk] = ss;
  }
}

// ---------------- per-(sample,cluster) masked Markowitz solve ----------------
__global__ __launch_bounds__(256) void nco_csolve_kernel(
    const float* __restrict__ cov, const float* __restrict__ rets,
    const int* __restrict__ ixsAll, const double* __restrict__ inertiaAll,
    double* __restrict__ gbuf_all, double* __restrict__ wc_all) {
  int b = blockIdx.x;                 // j*NC + c
  int j = b >> 3, c = b & 7;
  int t = threadIdx.x;
  const float* C = cov + (size_t)j * NA * NA;
  const float* r = rets + (size_t)j * NA;

  __shared__ double bufl[MLDS * MLDS];            // 64.8 KiB
  __shared__ int    li[NA];
  __shared__ int    sm, soff, sbest;
  __shared__ double rhs[NA];
  __shared__ double wsub[NA];
  __shared__ double sdenom;

  if (t == 0) {
    double bv = inertiaAll[j * NI]; int bb = 0;
    for (int m = 1; m < NI; m++) {
      double v = inertiaAll[j * NI + m];
      if (v < bv) { bv = v; bb = m; }             // first-min
    }
    sbest = bb;
  }
  __syncthreads();
  const int* ixs = ixsAll + (size_t)(j * NI + sbest) * NA;

  double* wcc = wc_all + ((size_t)j * NC + c) * NA;
  wcc[t] = 0.0;

  if (t == 0) {
    int cnt[NC] = {0, 0, 0, 0, 0, 0, 0, 0};
    for (int i = 0; i < NA; i++) cnt[ixs[i]]++;
    int off = 0;
    for (int u = 0; u < c; u++) off += cnt[u] * cnt[u];   // packed: sum m^2 <= 256^2
    soff = off;
    int m2 = 0;
    for (int i = 0; i < NA; i++) if (ixs[i] == c) li[m2++] = i;
    sm = m2;
  }
  __syncthreads();
  int m = sm;
  if (m == 0) return;                  // uniform exit; column stays zero

  double* bp = (m <= MLDS) ? bufl : (gbuf_all + (size_t)j * NA * NA + soff);
  if (t < m) {
    int ra = li[t];
    const float* Crow = C + (size_t)ra * NA;
    for (int b2 = 0; b2 < m; b2++) bp[(size_t)t * m + b2] = (double)Crow[li[b2]];
    rhs[t] = (double)r[ra];
  }
  __syncthreads();
  // Gaussian elimination (SPD submatrix -> no pivoting)
  for (int k = 0; k < m - 1; k++) {
    double piv = bp[(size_t)k * m + k];
    if (t > k && t < m) {
      double f = bp[(size_t)t * m + k] / piv;
      rhs[t] -= f * rhs[k];
      for (int b2 = k + 1; b2 < m; b2++)
        bp[(size_t)t * m + b2] -= f * bp[(size_t)k * m + b2];
    }
    __syncthreads();
  }
  // back substitution
  for (int a = m - 1; a >= 0; a--) {
    if (t == a) wsub[a] = rhs[a] / bp[(size_t)a * m + a];
    __syncthreads();
    if (t < a) rhs[t] -= bp[(size_t)t * m + a] * wsub[a];
    __syncthreads();
  }
  if (t == 0) {
    double ssum = 0.0;
    for (int a = 0; a < m; a++) ssum += wsub[a];
    sdenom = ssum;
  }
  __syncthreads();
  if (t < m) wcc[li[t]] = (sdenom != 0.0) ? (wsub[t] / sdenom) : 0.0;
}

// ---------------- per-sample inter-cluster assembly + output ----------------
__global__ __launch_bounds__(256) void nco_inter_kernel(
    const float* __restrict__ cov, const float* __restrict__ rets,
    const double* __restrict__ wc_all, float* __restrict__ out) {
  int j = blockIdx.x, t = threadIdx.x;
  const float* C = cov + (size_t)j * NA * NA;
  const float* r = rets + (size_t)j * NA;

  __shared__ double wc[NC][NA];
  __shared__ double tmpL[NC][NA];
  __shared__ double interA[NC][NC];
  __shared__ double interb[NC];
  __shared__ double wi[NC];

  for (int c = 0; c < NC; c++) wc[c][t] = wc_all[((size_t)j * NC + c) * NA + t];
  __syncthreads();

  {
    double tcol[NC];
#pragma unroll
    for (int c = 0; c < NC; c++) tcol[c] = 0.0;
    for (int p = 0; p < NA; p++) {
      double cv = (double)C[(size_t)p * NA + t];
#pragma unroll
      for (int c = 0; c < NC; c++) tcol[c] += wc[c][p] * cv;
    }
#pragma unroll
    for (int c = 0; c < NC; c++) tmpL[c][t] = tcol[c];
  }
  __syncthreads();

  if (t < NC * NC) {
    int c = t / NC, c2 = t % NC;
    double s = 0.0;
    for (int q = 0; q < NA; q++) s += tmpL[c][q] * wc[c2][q];
    interA[c][c2] = s;
  }
  if (t >= 64 && t < 64 + NC) {
    int c = t - 64;
    double s = 0.0;
    for (int p = 0; p < NA; p++) s += wc[c][p] * (double)r[p];
    interb[c] = s;
  }
  __syncthreads();

  if (t == 0) {
    double A[NC][NC], bb[NC];
    for (int a = 0; a < NC; a++) {
      bb[a] = interb[a];
      for (int q = 0; q < NC; q++) A[a][q] = interA[a][q];
    }
    for (int k = 0; k < NC; k++) {
      int p = k; double mx = fabs(A[k][k]);
      for (int i2 = k + 1; i2 < NC; i2++) {
        double v = fabs(A[i2][k]);
        if (v > mx) { mx = v; p = i2; }
      }
      if (p != k) {
        for (int q = 0; q < NC; q++) { double tv = A[k][q]; A[k][q] = A[p][q]; A[p][q] = tv; }
        double tb = bb[k]; bb[k] = bb[p]; bb[p] = tb;
      }
      for (int i2 = k + 1; i2 < NC; i2++) {
        double f = A[i2][k] / A[k][k];
        bb[i2] -= f * bb[k];
        for (int q = k + 1; q < NC; q++) A[i2][q] -= f * A[k][q];
      }
    }
    double w[NC];
    for (int a = NC - 1; a >= 0; a--) {
      double s = bb[a];
      for (int q = a + 1; q < NC; q++) s -= A[a][q] * w[q];
      w[a] = s / A[a][a];
    }
    double ssum = 0.0;
    for (int a = 0; a < NC; a++) ssum += w[a];
    for (int a = 0; a < NC; a++) wi[a] = w[a] / ssum;
  }
  __syncthreads();

  double o = 0.0;
#pragma unroll
  for (int c = 0; c < NC; c++) o += wc[c][t] * wi[c];
  out[(size_t)j * NA + t] = (float)o;
}

extern "C" void kernel_launch(void* const* d_in, const int* in_sizes, int n_in,
                              void* d_out, int out_size, void* d_ws, size_t ws_size,
                              hipStream_t stream) {
  const float* cov  = (const float*)d_in[0];
  const float* rets = (const float*)d_in[1];
  float* out = (float*)d_out;
  char* ws = (char*)d_ws;

  const size_t g_bytes = (size_t)NS * NA * NA * sizeof(double);        // 32 MiB
  double* G          = (double*)(ws);
  double* invs       = (double*)(ws + g_bytes);                        // 128 KiB
  int*    initIdx    = (int*)   (ws + g_bytes + 131072);               // 20 KiB
  double* inertiaAll = (double*)(ws + g_bytes + 131072 + 20480);       // 5 KiB
  int*    ixsAll     = (int*)   (ws + g_bytes + 131072 + 20480 + 5120);
  double* wc_all     = (double*)(ws + g_bytes + 131072 + 20480 + 5120 + 655360);
  double* gbuf_all   = G;       // alias: G dead after kmeans

  hipLaunchKernelGGL(nco_invs_kernel,   dim3(NS),      dim3(NA), 0, stream, cov, invs);
  hipLaunchKernelGGL(nco_gram_kernel,   dim3(NS * 16), dim3(NA), 0, stream, cov, invs, G);
  hipLaunchKernelGGL(nco_init_kernel,   dim3(NS * NI), dim3(NA), 0, stream, initIdx);
  hipLaunchKernelGGL(nco_kmeans_kernel, dim3(NS * NI), dim3(NA), 0, stream,
                     G, initIdx, ixsAll, inertiaAll);
  hipLaunchKernelGGL(nco_csolve_kernel, dim3(NS * NC), dim3(NA), 0, stream,
                     cov, rets, ixsAll, inertiaAll, gbuf_all, wc_all);
  hipLaunchKernelGGL(nco_inter_kernel,  dim3(NS),      dim3(NA), 0, stream,
                     cov, rets, wc_all, out);
}

// Round 7
// 479.735 us; speedup vs baseline: 16.2407x; 1.0561x over previous
//
#include <hip/hip_runtime.h>
#include <stdint.h>

#define NS 64      // samples
#define NA 256     // assets
#define NC 8       // clusters
#define NI 10      // inits
#define MAXIT 30   // lloyd iterations
#define MLDS 90    // solve: max cluster size for LDS-resident elimination

typedef unsigned int u32;

struct Key { u32 x, y; };

// Threefry-2x32, 20 rounds — exact JAX semantics.
__device__ __forceinline__ void tf2x32(u32 k0, u32 k1, u32 c0, u32 c1, u32& o0, u32& o1) {
  u32 ks0 = k0, ks1 = k1, ks2 = k0 ^ k1 ^ 0x1BD11BDAu;
  u32 x0 = c0 + ks0, x1 = c1 + ks1;
#define TFR(r) { x0 += x1; x1 = (x1 << (r)) | (x1 >> (32 - (r))); x1 ^= x0; }
  TFR(13) TFR(15) TFR(26) TFR(6)
  x0 += ks1; x1 += ks2 + 1u;
  TFR(17) TFR(29) TFR(16) TFR(24)
  x0 += ks2; x1 += ks0 + 2u;
  TFR(13) TFR(15) TFR(26) TFR(6)
  x0 += ks0; x1 += ks1 + 3u;
  TFR(17) TFR(29) TFR(16) TFR(24)
  x0 += ks1; x1 += ks2 + 4u;
  TFR(13) TFR(15) TFR(26) TFR(6)
  x0 += ks2; x1 += ks0 + 5u;
#undef TFR
  o0 = x0; o1 = x1;
}

// jax_threefry_partitionable=True semantics (verified round 2):
// split(key, n)[j]              = threefry2x32(key, 0, j) -> (o0, o1)
// random_bits(key, 32, (n,))[i] = o0 ^ o1 of threefry2x32(key, 0, i)
__device__ __forceinline__ Key key_row(Key k, u32 j) {
  Key r; tf2x32(k.x, k.y, 0u, j, r.x, r.y); return r;
}
__device__ __forceinline__ u32 rbits32(Key k, u32 i) {
  u32 o0, o1; tf2x32(k.x, k.y, 0u, i, o0, o1); return o0 ^ o1;
}

// ---------------- Gram G = corr * corr^T (f64), triangle-only, fused diag ------------
__global__ __launch_bounds__(256) void nco_gram_kernel(
    const float* __restrict__ cov, double* __restrict__ G) {
  int b = blockIdx.x;                 // j*10 + tile
  int j = b / 10, tile = b - 10 * j;
  const int TIa[10] = {0,0,0,0,1,1,1,2,2,3};
  const int TJa[10] = {0,1,2,3,1,2,3,2,3,3};
  int ti2 = TIa[tile], tj2 = TJa[tile];
  const float* C = cov + (size_t)j * NA * NA;
  double* Gj = G + (size_t)j * NA * NA;

  __shared__ double sinv[NA];
  __shared__ double As[16][64 + 1];   // As[kk][row]
  __shared__ double Bs[16][64 + 1];
  int t = threadIdx.x;
  int tr = t >> 4, tc = t & 15;       // 16x16 thread tile, each 4x4 out

  sinv[t] = 1.0 / sqrt((double)C[(size_t)t * NA + t]);
  __syncthreads();

  double acc[4][4];
#pragma unroll
  for (int a = 0; a < 4; a++)
#pragma unroll
    for (int bb = 0; bb < 4; bb++) acc[a][bb] = 0.0;

  for (int k0 = 0; k0 < NA; k0 += 16) {
    int kk = t & 15, rr = t >> 4;
    double ck = sinv[k0 + kk];
#pragma unroll
    for (int m = 0; m < 4; m++) {
      int r = rr + 16 * m;
      int gr = ti2 * 64 + r;
      As[kk][r] = (double)C[(size_t)gr * NA + k0 + kk] * sinv[gr] * ck;
      int gc = tj2 * 64 + r;
      Bs[kk][r] = (double)C[(size_t)gc * NA + k0 + kk] * sinv[gc] * ck;
    }
    __syncthreads();
#pragma unroll
    for (int kk2 = 0; kk2 < 16; kk2++) {
      double ar[4], br[4];
#pragma unroll
      for (int m = 0; m < 4; m++) ar[m] = As[kk2][tr + 16 * m];
#pragma unroll
      for (int m = 0; m < 4; m++) br[m] = Bs[kk2][tc + 16 * m];
#pragma unroll
      for (int a = 0; a < 4; a++)
#pragma unroll
        for (int bb = 0; bb < 4; bb++) acc[a][bb] = fma(ar[a], br[bb], acc[a][bb]);
    }
    __syncthreads();
  }
#pragma unroll
  for (int a = 0; a < 4; a++) {
    int gr = ti2 * 64 + tr + 16 * a;
#pragma unroll
    for (int bb = 0; bb < 4; bb++) {
      int gc = tj2 * 64 + tc + 16 * bb;
      Gj[(size_t)gr * NA + gc] = acc[a][bb];
      if (ti2 != tj2) Gj[(size_t)gc * NA + gr] = acc[a][bb];  // symmetry mirror
    }
  }
}

// ---------------- k-means (Gram sums, 512-thr split sweep, fused init) ----------------
// score_k(t) = S_k/n_k^2 - 2 s_k[t]/n_k with s_k[t] = sum_{i in list_k} G[i][t].
// Group 0 (tid<256) owns per-point state; group 1 sums the upper half of each
// list. Frozen-empty-cluster semantics via list/size freeze. Early exit at the
// assignment fixed point is bit-exact. XCD swizzle: 8 samples (4 MiB) per L2.
__global__ __launch_bounds__(512) void nco_kmeans_kernel(
    const double* __restrict__ G, int* __restrict__ ixsAll,
    double* __restrict__ inertiaAll) {
  int b = blockIdx.x;                 // 0..639
  int xcd = b & 7, s = b >> 3;
  int j  = xcd + 8 * (s / NI);        // sample (bijective)
  int mi = s - (s / NI) * NI;         // init
  int blk = j * NI + mi;
  int tid = threadIdx.x;
  int t = tid & 255;                  // point
  int g = tid >> 8;                   // sweep group
  int w4 = tid >> 6;                  // wave (0..3 in group 0)
  const double* Gj = G + (size_t)j * NA * NA;

  __shared__ int    li[NC][NA];       // member lists
  __shared__ double sAll[NC][NA];     // combined s_k[t]
  __shared__ double sB[NC][NA];       // group-1 partials
  __shared__ int    wcnt[4][NC];
  __shared__ int    nsz[NC];
  __shared__ double part[NC][8];
  __shared__ double sinvn[NC], ck2[NC];
  __shared__ int    wch[4];
  __shared__ u32    bits[NA];

  // fused init: JAX PRNG chain + stable-rank top-8 (choice without replacement)
  if (g == 0) {
    Key base; base.x = 0u; base.y = 42u;        // jax.random.key(42)
    Key skey = key_row(base, (u32)j);           // split(base, 64)[j]
    Key ikey = key_row(skey, (u32)mi);          // split(skey, 10)[mi]
    Key sub  = key_row(ikey, 1u);               // _shuffle subkey
    bits[t] = rbits32(sub, (u32)t);
  }
  __syncthreads();
  if (g == 0) {
    u32 mine = bits[t];
    int rank = 0;
    for (int u = 0; u < NA; u++) {
      u32 b2 = bits[u];
      rank += (b2 < mine) || (b2 == mine && u < t);
    }
    if (rank < NC) li[rank][0] = t;
    if (t < NC) nsz[t] = 1;
  }
  __syncthreads();

  double xx = (g == 0) ? Gj[(size_t)t * NA + t] : 0.0;  // ||x_t||^2
  int myix = -1;
  double fb = 0.0;
  for (int it = 0; it <= MAXIT; ++it) {
    if (it > 0) {
      unsigned long long mybal = 0;
      if (g == 0) {
#pragma unroll
        for (int k = 0; k < NC; k++) {
          unsigned long long bal = __ballot(myix == k);
          if ((t & 63) == 0) wcnt[w4][k] = (int)__popcll(bal);
          if (k == myix) mybal = bal;
        }
      }
      __syncthreads();                 // (A)
      if (g == 0) {
        if (t < NC) {
          int tot = wcnt[0][t] + wcnt[1][t] + wcnt[2][t] + wcnt[3][t];
          if (tot > 0) nsz[t] = tot;   // empty -> frozen list/size
        }
        int k = myix;                  // my cluster is non-empty
        int base = 0;
        for (int w2 = 0; w2 < w4; w2++) base += wcnt[w2][k];
        li[k][base + (int)__popcll(mybal & ((1ULL << (t & 63)) - 1ULL))] = t;
      }
      __syncthreads();                 // (B)
    }

    // split sweep: group g sums its half of each list (coalesced row reads)
    double acc[NC];
#pragma unroll
    for (int k = 0; k < NC; k++) {
      int n = nsz[k];
      int nh = n >> 1;
      int lo = g ? nh : 0;
      int hi = g ? n : nh;
      const int* lk = li[k];
      double a0 = 0.0, a1 = 0.0;
      int i = lo;
      for (; i + 4 <= hi; i += 4) {
        int r0 = lk[i], r1 = lk[i + 1], r2 = lk[i + 2], r3 = lk[i + 3];
        double g0 = Gj[(size_t)r0 * NA + t];
        double g1 = Gj[(size_t)r1 * NA + t];
        double g2 = Gj[(size_t)r2 * NA + t];
        double g3 = Gj[(size_t)r3 * NA + t];
        a0 += g0; a1 += g1; a0 += g2; a1 += g3;
      }
      for (; i < hi; ++i) a0 += Gj[(size_t)lk[i] * NA + t];
      acc[k] = a0 + a1;
    }
    if (g == 1) {
#pragma unroll
      for (int k = 0; k < NC; k++) sB[k][t] = acc[k];
    }
    __syncthreads();                   // (C)
    if (g == 0) {
#pragma unroll
      for (int k = 0; k < NC; k++) { acc[k] += sB[k][t]; sAll[k][t] = acc[k]; }
    }
    __syncthreads();                   // (D)

    // S_k = sum_{t in list_k} s_k[t]
    if (tid < 64) {
      int k = tid >> 3, r = tid & 7;
      int n = nsz[k];
      double p = 0.0;
      for (int i = r; i < n; i += 8) p += sAll[k][li[k][i]];
      part[k][r] = p;
    }
    __syncthreads();                   // (E)
    if (tid < NC) {
      double S = 0.0;
#pragma unroll
      for (int r = 0; r < 8; r++) S += part[tid][r];
      double inn = 1.0 / (double)nsz[tid];
      sinvn[tid] = inn;
      ck2[tid] = S * inn * inn;
    }
    __syncthreads();                   // (F)

    if (g == 0) {
      double best = ck2[0] - 2.0 * acc[0] * sinvn[0]; int bi = 0;
#pragma unroll
      for (int k = 1; k < NC; k++) {
        double f = ck2[k] - 2.0 * acc[k] * sinvn[k];
        if (f < best) { best = f; bi = k; }   // first-min = jnp.argmin
      }
      fb = best;
      bool ch = (bi != myix);
      unsigned long long balc = __ballot(ch);
      if ((t & 63) == 0) wch[w4] = (balc != 0ULL) ? 1 : 0;
      myix = bi;
    }
    __syncthreads();                   // (G)
    if (!(wch[0] | wch[1] | wch[2] | wch[3])) break;   // fixed point: bit-exact
  }

  double* red = &sB[0][0];
  if (g == 0) red[t] = xx + fb;        // min d^2 of point t
  __syncthreads();
  if (g == 0) ixsAll[blk * NA + t] = myix;
  if (tid == 0) {
    double ss = 0.0;
    for (int i = 0; i < NA; i++) ss += red[i];   // exact i-order
    inertiaAll[blk] = ss;
  }
}

// ---------------- per-(sample,cluster) masked Markowitz solve ----------------
__global__ __launch_bounds__(256) void nco_csolve_kernel(
    const float* __restrict__ cov, const float* __restrict__ rets,
    const int* __restrict__ ixsAll, const double* __restrict__ inertiaAll,
    double* __restrict__ gbuf_all, double* __restrict__ wc_all) {
  int b = blockIdx.x;                 // j*NC + c
  int j = b >> 3, c = b & 7;
  int t = threadIdx.x, w = t >> 6;
  const float* C = cov + (size_t)j * NA * NA;
  const float* r = rets + (size_t)j * NA;

  __shared__ double bufl[MLDS * MLDS];            // 64.8 KiB
  __shared__ int    li[NA];
  __shared__ int    wcnt[4][NC];
  __shared__ int    scnt[NC];
  __shared__ int    sbest;
  __shared__ double rhs[NA];
  __shared__ double wsub[NA];
  __shared__ double sdenom;

  if (t == 0) {
    double bv = inertiaAll[j * NI]; int bb = 0;
    for (int m = 1; m < NI; m++) {
      double v = inertiaAll[j * NI + m];
      if (v < bv) { bv = v; bb = m; }             // first-min
    }
    sbest = bb;
  }
  __syncthreads();
  const int* ixs = ixsAll + (size_t)(j * NI + sbest) * NA;

  // parallel cluster counts + member list (ascending order via ballot/popcount)
  int myc = ixs[t];
  unsigned long long mybal = 0;
#pragma unroll
  for (int u = 0; u < NC; u++) {
    unsigned long long bal = __ballot(myc == u);
    if ((t & 63) == 0) wcnt[w][u] = (int)__popcll(bal);
    if (u == myc) mybal = bal;
  }
  __syncthreads();
  if (t < NC) scnt[t] = wcnt[0][t] + wcnt[1][t] + wcnt[2][t] + wcnt[3][t];
  __syncthreads();
  if (myc == c) {
    int base = 0;
    for (int w2 = 0; w2 < w; w2++) base += wcnt[w2][c];
    li[base + (int)__popcll(mybal & ((1ULL << (t & 63)) - 1ULL))] = t;
  }
  double* wcc = wc_all + ((size_t)j * NC + c) * NA;
  wcc[t] = 0.0;
  __syncthreads();

  int m = scnt[c];
  if (m == 0) return;                  // uniform exit; column stays zero

  int soff = 0;
  for (int u = 0; u < c; u++) soff += scnt[u] * scnt[u];  // packed: sum m^2 <= 256^2
  double* bp = (m <= MLDS) ? bufl : (gbuf_all + (size_t)j * NA * NA + soff);

  // flat 256-thread staging of the m x m submatrix
  for (int idx = t; idx < m * m; idx += NA) {
    int row = idx / m, col = idx - row * m;
    bp[idx] = (double)C[(size_t)li[row] * NA + li[col]];
  }
  if (t < m) rhs[t] = (double)r[li[t]];
  __syncthreads();

  // Gaussian elimination (SPD submatrix -> no pivoting)
  for (int k = 0; k < m - 1; k++) {
    double piv = bp[(size_t)k * m + k];
    if (t > k && t < m) {
      double f = bp[(size_t)t * m + k] / piv;
      rhs[t] -= f * rhs[k];
      for (int b2 = k + 1; b2 < m; b2++)
        bp[(size_t)t * m + b2] -= f * bp[(size_t)k * m + b2];
    }
    __syncthreads();
  }
  // back substitution
  for (int a = m - 1; a >= 0; a--) {
    if (t == a) wsub[a] = rhs[a] / bp[(size_t)a * m + a];
    __syncthreads();
    if (t < a) rhs[t] -= bp[(size_t)t * m + a] * wsub[a];
    __syncthreads();
  }
  if (t == 0) {
    double ssum = 0.0;
    for (int a = 0; a < m; a++) ssum += wsub[a];
    sdenom = ssum;
  }
  __syncthreads();
  if (t < m) wcc[li[t]] = (sdenom != 0.0) ? (wsub[t] / sdenom) : 0.0;
}

// ---------------- per-sample inter-cluster assembly + output ----------------
__global__ __launch_bounds__(256) void nco_inter_kernel(
    const float* __restrict__ cov, const float* __restrict__ rets,
    const double* __restrict__ wc_all, float* __restrict__ out) {
  int j = blockIdx.x, t = threadIdx.x;
  const float* C = cov + (size_t)j * NA * NA;
  const float* r = rets + (size_t)j * NA;

  __shared__ double wc[NC][NA];
  __shared__ double tmpL[NC][NA];
  __shared__ double interA[NC][NC];
  __shared__ double interb[NC];
  __shared__ double wi[NC];

  for (int c = 0; c < NC; c++) wc[c][t] = wc_all[((size_t)j * NC + c) * NA + t];
  __syncthreads();

  {
    double tcol[NC];
#pragma unroll
    for (int c = 0; c < NC; c++) tcol[c] = 0.0;
    for (int p = 0; p < NA; p++) {
      double cv = (double)C[(size_t)p * NA + t];
#pragma unroll
      for (int c = 0; c < NC; c++) tcol[c] += wc[c][p] * cv;
    }
#pragma unroll
    for (int c = 0; c < NC; c++) tmpL[c][t] = tcol[c];
  }
  __syncthreads();

  if (t < NC * NC) {
    int c = t / NC, c2 = t % NC;
    double s = 0.0;
    for (int q = 0; q < NA; q++) s += tmpL[c][q] * wc[c2][q];
    interA[c][c2] = s;
  }
  if (t >= 64 && t < 64 + NC) {
    int c = t - 64;
    double s = 0.0;
    for (int p = 0; p < NA; p++) s += wc[c][p] * (double)r[p];
    interb[c] = s;
  }
  __syncthreads();

  if (t == 0) {
    double A[NC][NC], bb[NC];
    for (int a = 0; a < NC; a++) {
      bb[a] = interb[a];
      for (int q = 0; q < NC; q++) A[a][q] = interA[a][q];
    }
    for (int k = 0; k < NC; k++) {
      int p = k; double mx = fabs(A[k][k]);
      for (int i2 = k + 1; i2 < NC; i2++) {
        double v = fabs(A[i2][k]);
        if (v > mx) { mx = v; p = i2; }
      }
      if (p != k) {
        for (int q = 0; q < NC; q++) { double tv = A[k][q]; A[k][q] = A[p][q]; A[p][q] = tv; }
        double tb = bb[k]; bb[k] = bb[p]; bb[p] = tb;
      }
      for (int i2 = k + 1; i2 < NC; i2++) {
        double f = A[i2][k] / A[k][k];
        bb[i2] -= f * bb[k];
        for (int q = k + 1; q < NC; q++) A[i2][q] -= f * A[k][q];
      }
    }
    double w[NC];
    for (int a = NC - 1; a >= 0; a--) {
      double s = bb[a];
      for (int q = a + 1; q < NC; q++) s -= A[a][q] * w[q];
      w[a] = s / A[a][a];
    }
    double ssum = 0.0;
    for (int a = 0; a < NC; a++) ssum += w[a];
    for (int a = 0; a < NC; a++) wi[a] = w[a] / ssum;
  }
  __syncthreads();

  double o = 0.0;
#pragma unroll
  for (int c = 0; c < NC; c++) o += wc[c][t] * wi[c];
  out[(size_t)j * NA + t] = (float)o;
}

extern "C" void kernel_launch(void* const* d_in, const int* in_sizes, int n_in,
                              void* d_out, int out_size, void* d_ws, size_t ws_size,
                              hipStream_t stream) {
  const float* cov  = (const float*)d_in[0];
  const float* rets = (const float*)d_in[1];
  float* out = (float*)d_out;
  char* ws = (char*)d_ws;

  const size_t g_bytes = (size_t)NS * NA * NA * sizeof(double);        // 32 MiB
  double* G          = (double*)(ws);
  double* inertiaAll = (double*)(ws + g_bytes);                        // 5 KiB
  int*    ixsAll     = (int*)   (ws + g_bytes + 5120);                 // 640 KiB
  double* wc_all     = (double*)(ws + g_bytes + 5120 + 655360);        // 1 MiB
  double* gbuf_all   = G;       // alias: G dead after kmeans

  hipLaunchKernelGGL(nco_gram_kernel,   dim3(NS * 10), dim3(NA),  0, stream, cov, G);
  hipLaunchKernelGGL(nco_kmeans_kernel, dim3(NS * NI), dim3(512), 0, stream,
                     G, ixsAll, inertiaAll);
  hipLaunchKernelGGL(nco_csolve_kernel, dim3(NS * NC), dim3(NA),  0, stream,
                     cov, rets, ixsAll, inertiaAll, gbuf_all, wc_all);
  hipLaunchKernelGGL(nco_inter_kernel,  dim3(NS),      dim3(NA),  0, stream,
                     cov, rets, wc_all, out);
}

// Round 8
// 390.658 us; speedup vs baseline: 19.9439x; 1.2280x over previous
//
#include <hip/hip_runtime.h>
#include <stdint.h>

#define NS 64      // samples
#define NA 256     // assets
#define NC 8       // clusters
#define NI 10      // inits
#define MAXIT 30   // lloyd iterations
#define MLDS 90    // solve: max cluster size for LDS-resident elimination

typedef unsigned int u32;
typedef unsigned long long u64;

struct Key { u32 x, y; };

// Threefry-2x32, 20 rounds — exact JAX semantics.
__device__ __forceinline__ void tf2x32(u32 k0, u32 k1, u32 c0, u32 c1, u32& o0, u32& o1) {
  u32 ks0 = k0, ks1 = k1, ks2 = k0 ^ k1 ^ 0x1BD11BDAu;
  u32 x0 = c0 + ks0, x1 = c1 + ks1;
#define TFR(r) { x0 += x1; x1 = (x1 << (r)) | (x1 >> (32 - (r))); x1 ^= x0; }
  TFR(13) TFR(15) TFR(26) TFR(6)
  x0 += ks1; x1 += ks2 + 1u;
  TFR(17) TFR(29) TFR(16) TFR(24)
  x0 += ks2; x1 += ks0 + 2u;
  TFR(13) TFR(15) TFR(26) TFR(6)
  x0 += ks0; x1 += ks1 + 3u;
  TFR(17) TFR(29) TFR(16) TFR(24)
  x0 += ks1; x1 += ks2 + 4u;
  TFR(13) TFR(15) TFR(26) TFR(6)
  x0 += ks2; x1 += ks0 + 5u;
#undef TFR
  o0 = x0; o1 = x1;
}

// jax_threefry_partitionable=True semantics (verified round 2):
// split(key, n)[j]              = threefry2x32(key, 0, j) -> (o0, o1)
// random_bits(key, 32, (n,))[i] = o0 ^ o1 of threefry2x32(key, 0, i)
__device__ __forceinline__ Key key_row(Key k, u32 j) {
  Key r; tf2x32(k.x, k.y, 0u, j, r.x, r.y); return r;
}
__device__ __forceinline__ u32 rbits32(Key k, u32 i) {
  u32 o0, o1; tf2x32(k.x, k.y, 0u, i, o0, o1); return o0 ^ o1;
}

// ---------------- Gram G = corr * corr^T (f64), triangle-only, fused diag ------------
__global__ __launch_bounds__(256) void nco_gram_kernel(
    const float* __restrict__ cov, double* __restrict__ G) {
  int b = blockIdx.x;                 // j*10 + tile
  int j = b / 10, tile = b - 10 * j;
  const int TIa[10] = {0,0,0,0,1,1,1,2,2,3};
  const int TJa[10] = {0,1,2,3,1,2,3,2,3,3};
  int ti2 = TIa[tile], tj2 = TJa[tile];
  const float* C = cov + (size_t)j * NA * NA;
  double* Gj = G + (size_t)j * NA * NA;

  __shared__ double sinv[NA];
  __shared__ double As[16][64 + 1];   // As[kk][row]
  __shared__ double Bs[16][64 + 1];
  int t = threadIdx.x;
  int tr = t >> 4, tc = t & 15;       // 16x16 thread tile, each 4x4 out

  sinv[t] = 1.0 / sqrt((double)C[(size_t)t * NA + t]);
  __syncthreads();

  double acc[4][4];
#pragma unroll
  for (int a = 0; a < 4; a++)
#pragma unroll
    for (int bb = 0; bb < 4; bb++) acc[a][bb] = 0.0;

  for (int k0 = 0; k0 < NA; k0 += 16) {
    int kk = t & 15, rr = t >> 4;
    double ck = sinv[k0 + kk];
#pragma unroll
    for (int m = 0; m < 4; m++) {
      int r = rr + 16 * m;
      int gr = ti2 * 64 + r;
      As[kk][r] = (double)C[(size_t)gr * NA + k0 + kk] * sinv[gr] * ck;
      int gc = tj2 * 64 + r;
      Bs[kk][r] = (double)C[(size_t)gc * NA + k0 + kk] * sinv[gc] * ck;
    }
    __syncthreads();
#pragma unroll
    for (int kk2 = 0; kk2 < 16; kk2++) {
      double ar[4], br[4];
#pragma unroll
      for (int m = 0; m < 4; m++) ar[m] = As[kk2][tr + 16 * m];
#pragma unroll
      for (int m = 0; m < 4; m++) br[m] = Bs[kk2][tc + 16 * m];
#pragma unroll
      for (int a = 0; a < 4; a++)
#pragma unroll
        for (int bb = 0; bb < 4; bb++) acc[a][bb] = fma(ar[a], br[bb], acc[a][bb]);
    }
    __syncthreads();
  }
#pragma unroll
  for (int a = 0; a < 4; a++) {
    int gr = ti2 * 64 + tr + 16 * a;
#pragma unroll
    for (int bb = 0; bb < 4; bb++) {
      int gc = tj2 * 64 + tc + 16 * bb;
      Gj[(size_t)gr * NA + gc] = acc[a][bb];
      if (ti2 != tj2) Gj[(size_t)gc * NA + gr] = acc[a][bb];  // symmetry mirror
    }
  }
}

// ---------------- k-means (Gram sums + dirty-cluster caching + early exit) -----------
// score_k(t) = S_k/n_k^2 - 2 s_k[t]/n_k with s_k[t] = sum_{i in list_k} G[i][t].
// A cluster's s_k/S_k/n_k depend ONLY on its member list; lists are detected
// as changed via exact per-wave ballot comparison -> unchanged clusters skip
// the sweep (identical list => identical sums: bit-exact). Group 0 (tid<256)
// owns per-point state; group 1 sums the upper half of each dirty list.
// Frozen-empty-cluster semantics via list/size freeze. Early exit at the
// assignment fixed point is bit-exact. XCD swizzle: 8 samples (4 MiB) per L2.
__global__ __launch_bounds__(512) void nco_kmeans_kernel(
    const double* __restrict__ G, int* __restrict__ ixsAll,
    double* __restrict__ inertiaAll) {
  int b = blockIdx.x;                 // 0..639
  int xcd = b & 7, s = b >> 3;
  int j  = xcd + 8 * (s / NI);        // sample (bijective)
  int mi = s - (s / NI) * NI;         // init
  int blk = j * NI + mi;
  int tid = threadIdx.x;
  int t = tid & 255;                  // point
  int g = tid >> 8;                   // sweep group
  int w4 = tid >> 6;                  // wave (0..3 in group 0)
  const double* Gj = G + (size_t)j * NA * NA;

  __shared__ int    li[NC][NA];       // member lists
  __shared__ double sA[NC][NA];       // group-0 partial s_k[t] (persistent)
  __shared__ double sB[NC][NA];       // group-1 partial s_k[t] (persistent)
  __shared__ int    wcnt[4][NC];
  __shared__ u64    balPrev[4][NC];   // ballots of the CURRENT list contents
  __shared__ u64    balNew[4][NC];
  __shared__ int    nsz[NC];
  __shared__ int    dirty[NC];
  __shared__ double part[NC][8];
  __shared__ double sinvn[NC], ck2[NC];  // persistent across iters
  __shared__ int    wch[4];
  __shared__ u32    bits[NA];

  // fused init: JAX PRNG chain + stable-rank top-8 (choice without replacement)
  if (g == 0) {
    Key base; base.x = 0u; base.y = 42u;        // jax.random.key(42)
    Key skey = key_row(base, (u32)j);           // split(base, 64)[j]
    Key ikey = key_row(skey, (u32)mi);          // split(skey, 10)[mi]
    Key sub  = key_row(ikey, 1u);               // _shuffle subkey
    bits[t] = rbits32(sub, (u32)t);
  }
  __syncthreads();
  int rank = NA;
  if (g == 0) {
    u32 mine = bits[t];
    rank = 0;
    for (int u = 0; u < NA; u++) {
      u32 b2 = bits[u];
      rank += (b2 < mine) || (b2 == mine && u < t);
    }
    if (rank < NC) li[rank][0] = t;
    if (t < NC) { nsz[t] = 1; dirty[t] = 1; }
    // seed balPrev with the singleton lists' exact ballots
#pragma unroll
    for (int k = 0; k < NC; k++) {
      u64 bal = __ballot(rank == k);
      if ((t & 63) == 0) balPrev[w4][k] = bal;
    }
  }
  __syncthreads();

  double xx = (g == 0) ? Gj[(size_t)t * NA + t] : 0.0;  // ||x_t||^2
  int myix = -1;
  double fb = 0.0;
  for (int it = 0; it <= MAXIT; ++it) {
    if (it > 0) {
      u64 mybal = 0;
      if (g == 0) {
#pragma unroll
        for (int k = 0; k < NC; k++) {
          u64 bal = __ballot(myix == k);
          if ((t & 63) == 0) { wcnt[w4][k] = (int)__popcll(bal); balNew[w4][k] = bal; }
          if (k == myix) mybal = bal;
        }
      }
      __syncthreads();                 // (A)
      if (g == 0) {
        if (t < NC) {
          int tot = wcnt[0][t] + wcnt[1][t] + wcnt[2][t] + wcnt[3][t];
          if (tot > 0) {
            nsz[t] = tot;
            bool d = (balNew[0][t] != balPrev[0][t]) | (balNew[1][t] != balPrev[1][t]) |
                     (balNew[2][t] != balPrev[2][t]) | (balNew[3][t] != balPrev[3][t]);
            dirty[t] = d ? 1 : 0;
            if (d) {                   // list will be rebuilt to match balNew
              balPrev[0][t] = balNew[0][t]; balPrev[1][t] = balNew[1][t];
              balPrev[2][t] = balNew[2][t]; balPrev[3][t] = balNew[3][t];
            }
          } else {
            dirty[t] = 0;              // empty -> frozen list/size/sums
          }
        }
        int k = myix;                  // my cluster is non-empty
        int base = 0;
        for (int w2 = 0; w2 < w4; w2++) base += wcnt[w2][k];
        li[k][base + (int)__popcll(mybal & ((1ULL << (t & 63)) - 1ULL))] = t;
      }
      __syncthreads();                 // (B)
    }

    // split sweep over DIRTY clusters only (coalesced row reads)
#pragma unroll
    for (int k = 0; k < NC; k++) {
      if (!dirty[k]) continue;
      int n = nsz[k];
      int nh = n >> 1;
      int lo = g ? nh : 0;
      int hi = g ? n : nh;
      const int* lk = li[k];
      double a0 = 0.0, a1 = 0.0;
      int i = lo;
      for (; i + 4 <= hi; i += 4) {
        int r0 = lk[i], r1 = lk[i + 1], r2 = lk[i + 2], r3 = lk[i + 3];
        double g0 = Gj[(size_t)r0 * NA + t];
        double g1 = Gj[(size_t)r1 * NA + t];
        double g2 = Gj[(size_t)r2 * NA + t];
        double g3 = Gj[(size_t)r3 * NA + t];
        a0 += g0; a1 += g1; a0 += g2; a1 += g3;
      }
      for (; i < hi; ++i) a0 += Gj[(size_t)lk[i] * NA + t];
      if (g) sB[k][t] = a0 + a1; else sA[k][t] = a0 + a1;
    }
    __syncthreads();                   // (C)

    // S_k partials for dirty clusters
    if (tid < 64) {
      int k = tid >> 3, r = tid & 7;
      if (dirty[k]) {
        int n = nsz[k];
        double p = 0.0;
        for (int i = r; i < n; i += 8) {
          int q = li[k][i];
          p += sA[k][q] + sB[k][q];
        }
        part[k][r] = p;
      }
    }
    __syncthreads();                   // (E)
    if (tid < NC && dirty[tid]) {
      double S = 0.0;
#pragma unroll
      for (int r = 0; r < 8; r++) S += part[tid][r];
      double inn = 1.0 / (double)nsz[tid];
      sinvn[tid] = inn;
      ck2[tid] = S * inn * inn;
    }
    __syncthreads();                   // (F)

    if (g == 0) {
      double best = ck2[0] - 2.0 * (sA[0][t] + sB[0][t]) * sinvn[0]; int bi = 0;
#pragma unroll
      for (int k = 1; k < NC; k++) {
        double f = ck2[k] - 2.0 * (sA[k][t] + sB[k][t]) * sinvn[k];
        if (f < best) { best = f; bi = k; }   // first-min = jnp.argmin
      }
      fb = best;
      bool ch = (bi != myix);
      u64 balc = __ballot(ch);
      if ((t & 63) == 0) wch[w4] = (balc != 0ULL) ? 1 : 0;
      myix = bi;
    }
    __syncthreads();                   // (G)
    if (!(wch[0] | wch[1] | wch[2] | wch[3])) break;   // fixed point: bit-exact
  }

  double* red = &bits[0] ? (double*)&part[0][0] : nullptr;  // (unused path guard)
  // inertia: exact i-order sum of min d^2
  __syncthreads();
  if (g == 0) ((double*)sB)[t] = xx + fb;   // sB reused as scratch (sweep done)
  __syncthreads();
  if (g == 0) ixsAll[blk * NA + t] = myix;
  if (tid == 0) {
    double ss = 0.0;
    for (int i = 0; i < NA; i++) ss += ((double*)sB)[i];
    inertiaAll[blk] = ss;
  }
}

// ---------------- per-(sample,cluster) masked Markowitz solve ----------------
__global__ __launch_bounds__(256) void nco_csolve_kernel(
    const float* __restrict__ cov, const float* __restrict__ rets,
    const int* __restrict__ ixsAll, const double* __restrict__ inertiaAll,
    double* __restrict__ gbuf_all, double* __restrict__ wc_all) {
  int b = blockIdx.x;                 // j*NC + c
  int j = b >> 3, c = b & 7;
  int t = threadIdx.x, w = t >> 6;
  const float* C = cov + (size_t)j * NA * NA;
  const float* r = rets + (size_t)j * NA;

  __shared__ double bufl[MLDS * MLDS];            // 64.8 KiB
  __shared__ int    li[NA];
  __shared__ int    wcnt[4][NC];
  __shared__ int    scnt[NC];
  __shared__ int    sbest;
  __shared__ double rhs[NA];
  __shared__ double wsub[NA];
  __shared__ double sdenom;

  if (t == 0) {
    double bv = inertiaAll[j * NI]; int bb = 0;
    for (int m = 1; m < NI; m++) {
      double v = inertiaAll[j * NI + m];
      if (v < bv) { bv = v; bb = m; }             // first-min
    }
    sbest = bb;
  }
  __syncthreads();
  const int* ixs = ixsAll + (size_t)(j * NI + sbest) * NA;

  // parallel cluster counts + member list (ascending order via ballot/popcount)
  int myc = ixs[t];
  u64 mybal = 0;
#pragma unroll
  for (int u = 0; u < NC; u++) {
    u64 bal = __ballot(myc == u);
    if ((t & 63) == 0) wcnt[w][u] = (int)__popcll(bal);
    if (u == myc) mybal = bal;
  }
  __syncthreads();
  if (t < NC) scnt[t] = wcnt[0][t] + wcnt[1][t] + wcnt[2][t] + wcnt[3][t];
  __syncthreads();
  if (myc == c) {
    int base = 0;
    for (int w2 = 0; w2 < w; w2++) base += wcnt[w2][c];
    li[base + (int)__popcll(mybal & ((1ULL << (t & 63)) - 1ULL))] = t;
  }
  double* wcc = wc_all + ((size_t)j * NC + c) * NA;
  wcc[t] = 0.0;
  __syncthreads();

  int m = scnt[c];
  if (m == 0) return;                  // uniform exit; column stays zero

  int soff = 0;
  for (int u = 0; u < c; u++) soff += scnt[u] * scnt[u];  // packed: sum m^2 <= 256^2
  double* bp = (m <= MLDS) ? bufl : (gbuf_all + (size_t)j * NA * NA + soff);

  // flat 256-thread staging of the m x m submatrix
  for (int idx = t; idx < m * m; idx += NA) {
    int row = idx / m, col = idx - row * m;
    bp[idx] = (double)C[(size_t)li[row] * NA + li[col]];
  }
  if (t < m) rhs[t] = (double)r[li[t]];
  __syncthreads();

  // Gaussian elimination (SPD submatrix -> no pivoting)
  for (int k = 0; k < m - 1; k++) {
    double piv = bp[(size_t)k * m + k];
    if (t > k && t < m) {
      double f = bp[(size_t)t * m + k] / piv;
      rhs[t] -= f * rhs[k];
      for (int b2 = k + 1; b2 < m; b2++)
        bp[(size_t)t * m + b2] -= f * bp[(size_t)k * m + b2];
    }
    __syncthreads();
  }
  // back substitution
  for (int a = m - 1; a >= 0; a--) {
    if (t == a) wsub[a] = rhs[a] / bp[(size_t)a * m + a];
    __syncthreads();
    if (t < a) rhs[t] -= bp[(size_t)t * m + a] * wsub[a];
    __syncthreads();
  }
  if (t == 0) {
    double ssum = 0.0;
    for (int a = 0; a < m; a++) ssum += wsub[a];
    sdenom = ssum;
  }
  __syncthreads();
  if (t < m) wcc[li[t]] = (sdenom != 0.0) ? (wsub[t] / sdenom) : 0.0;
}

// ---------------- per-sample inter-cluster assembly + output ----------------
__global__ __launch_bounds__(256) void nco_inter_kernel(
    const float* __restrict__ cov, const float* __restrict__ rets,
    const double* __restrict__ wc_all, float* __restrict__ out) {
  int j = blockIdx.x, t = threadIdx.x;
  const float* C = cov + (size_t)j * NA * NA;
  const float* r = rets + (size_t)j * NA;

  __shared__ double wc[NC][NA];
  __shared__ double tmpL[NC][NA];
  __shared__ double interA[NC][NC];
  __shared__ double interb[NC];
  __shared__ double wi[NC];

  for (int c = 0; c < NC; c++) wc[c][t] = wc_all[((size_t)j * NC + c) * NA + t];
  __syncthreads();

  {
    double tcol[NC];
#pragma unroll
    for (int c = 0; c < NC; c++) tcol[c] = 0.0;
    for (int p = 0; p < NA; p++) {
      double cv = (double)C[(size_t)p * NA + t];
#pragma unroll
      for (int c = 0; c < NC; c++) tcol[c] += wc[c][p] * cv;
    }
#pragma unroll
    for (int c = 0; c < NC; c++) tmpL[c][t] = tcol[c];
  }
  __syncthreads();

  if (t < NC * NC) {
    int c = t / NC, c2 = t % NC;
    double s = 0.0;
    for (int q = 0; q < NA; q++) s += tmpL[c][q] * wc[c2][q];
    interA[c][c2] = s;
  }
  if (t >= 64 && t < 64 + NC) {
    int c = t - 64;
    double s = 0.0;
    for (int p = 0; p < NA; p++) s += wc[c][p] * (double)r[p];
    interb[c] = s;
  }
  __syncthreads();

  if (t == 0) {
    double A[NC][NC], bb[NC];
    for (int a = 0; a < NC; a++) {
      bb[a] = interb[a];
      for (int q = 0; q < NC; q++) A[a][q] = interA[a][q];
    }
    for (int k = 0; k < NC; k++) {
      int p = k; double mx = fabs(A[k][k]);
      for (int i2 = k + 1; i2 < NC; i2++) {
        double v = fabs(A[i2][k]);
        if (v > mx) { mx = v; p = i2; }
      }
      if (p != k) {
        for (int q = 0; q < NC; q++) { double tv = A[k][q]; A[k][q] = A[p][q]; A[p][q] = tv; }
        double tb = bb[k]; bb[k] = bb[p]; bb[p] = tb;
      }
      for (int i2 = k + 1; i2 < NC; i2++) {
        double f = A[i2][k] / A[k][k];
        bb[i2] -= f * bb[k];
        for (int q = k + 1; q < NC; q++) A[i2][q] -= f * A[k][q];
      }
    }
    double w[NC];
    for (int a = NC - 1; a >= 0; a--) {
      double s = bb[a];
      for (int q = a + 1; q < NC; q++) s -= A[a][q] * w[q];
      w[a] = s / A[a][a];
    }
    double ssum = 0.0;
    for (int a = 0; a < NC; a++) ssum += w[a];
    for (int a = 0; a < NC; a++) wi[a] = w[a] / ssum;
  }
  __syncthreads();

  double o = 0.0;
#pragma unroll
  for (int c = 0; c < NC; c++) o += wc[c][t] * wi[c];
  out[(size_t)j * NA + t] = (float)o;
}

extern "C" void kernel_launch(void* const* d_in, const int* in_sizes, int n_in,
                              void* d_out, int out_size, void* d_ws, size_t ws_size,
                              hipStream_t stream) {
  const float* cov  = (const float*)d_in[0];
  const float* rets = (const float*)d_in[1];
  float* out = (float*)d_out;
  char* ws = (char*)d_ws;

  const size_t g_bytes = (size_t)NS * NA * NA * sizeof(double);        // 32 MiB
  double* G          = (double*)(ws);
  double* inertiaAll = (double*)(ws + g_bytes);                        // 5 KiB
  int*    ixsAll     = (int*)   (ws + g_bytes + 5120);                 // 640 KiB
  double* wc_all     = (double*)(ws + g_bytes + 5120 + 655360);        // 1 MiB
  double* gbuf_all   = G;       // alias: G dead after kmeans

  hipLaunchKernelGGL(nco_gram_kernel,   dim3(NS * 10), dim3(NA),  0, stream, cov, G);
  hipLaunchKernelGGL(nco_kmeans_kernel, dim3(NS * NI), dim3(512), 0, stream,
                     G, ixsAll, inertiaAll);
  hipLaunchKernelGGL(nco_csolve_kernel, dim3(NS * NC), dim3(NA),  0, stream,
                     cov, rets, ixsAll, inertiaAll, gbuf_all, wc_all);
  hipLaunchKernelGGL(nco_inter_kernel,  dim3(NS),      dim3(NA),  0, stream,
                     cov, rets, wc_all, out);
}